// Round 2
// baseline (1062.185 us; speedup 1.0000x reference)
//
#include <hip/hip_runtime.h>
#include <hip/hip_bf16.h>

#define Bq 4
#define Nq 2048
#define Cq 256
#define Dq 64
#define UPq 4
#define KNNq 20
#define PHq 64
#define DMq 256   // D*MULT
#define PTS 16    // points per block in k_value

__device__ __forceinline__ void ld16(float* d, const float* s){
  *reinterpret_cast<float4*>(d) = *reinterpret_cast<const float4*>(s);
}

// ---------------------------------------------------------------------------
// Kernel 1: value = MLP_Res(concat(key,query)); kf/qf/vf projections.
// Outputs stored point-major: valueT[b][n][c], kfT/qfT/vfT[b][n][o].
// ---------------------------------------------------------------------------
__global__ __launch_bounds__(256) void k_value(
    const float* __restrict__ key, const float* __restrict__ query,
    const float* __restrict__ wv1, const float* __restrict__ bv1,
    const float* __restrict__ wv2, const float* __restrict__ bv2,
    const float* __restrict__ wvs, const float* __restrict__ bvs,
    const float* __restrict__ wk,  const float* __restrict__ bk,
    const float* __restrict__ wq,  const float* __restrict__ bq,
    const float* __restrict__ wval,const float* __restrict__ bval,
    float* __restrict__ valueT, float* __restrict__ kfT,
    float* __restrict__ qfT,    float* __restrict__ vfT)
{
  __shared__ __align__(16) float keyL[Cq*PTS];
  __shared__ __align__(16) float qryL[Cq*PTS];
  __shared__ __align__(16) float hidL[Cq*PTS];
  __shared__ __align__(16) float valL[Cq*PTS];
  const int t  = threadIdx.x;           // == channel c
  const int blk = blockIdx.x;
  const int b  = blk >> 7;              // 128 blocks per batch (N/PTS)
  const int n0 = (blk & 127) * PTS;

  {
    const float* kp = key   + ((size_t)(b*Cq + t))*Nq + n0;
    const float* qp = query + ((size_t)(b*Cq + t))*Nq + n0;
    #pragma unroll
    for (int p=0;p<PTS;p+=4){
      ld16(&keyL[t*PTS+p], kp+p);
      ld16(&qryL[t*PTS+p], qp+p);
    }
  }
  __syncthreads();

  float acc1[PTS], acc2[PTS];
  #pragma unroll
  for (int p=0;p<PTS;p++){ acc1[p]=0.f; acc2[p]=0.f; }

  const float* w1  = wv1 + (size_t)t*(2*Cq);
  const float* wsp = wvs + (size_t)t*(2*Cq);
  for (int i=0;i<Cq;i++){
    float a = w1[i], s_ = wsp[i];
    float xv[PTS];
    ld16(&xv[0],  &keyL[i*PTS+0]);  ld16(&xv[4],  &keyL[i*PTS+4]);
    ld16(&xv[8],  &keyL[i*PTS+8]);  ld16(&xv[12], &keyL[i*PTS+12]);
    #pragma unroll
    for (int p=0;p<PTS;p++){ acc1[p]=fmaf(a,xv[p],acc1[p]); acc2[p]=fmaf(s_,xv[p],acc2[p]); }
  }
  for (int i=0;i<Cq;i++){
    float a = w1[Cq+i], s_ = wsp[Cq+i];
    float xv[PTS];
    ld16(&xv[0],  &qryL[i*PTS+0]);  ld16(&xv[4],  &qryL[i*PTS+4]);
    ld16(&xv[8],  &qryL[i*PTS+8]);  ld16(&xv[12], &qryL[i*PTS+12]);
    #pragma unroll
    for (int p=0;p<PTS;p++){ acc1[p]=fmaf(a,xv[p],acc1[p]); acc2[p]=fmaf(s_,xv[p],acc2[p]); }
  }
  float b1v = bv1[t];
  #pragma unroll
  for (int p=0;p<PTS;p++) hidL[t*PTS+p] = fmaxf(acc1[p]+b1v, 0.f);
  __syncthreads();

  const float* w2 = wv2 + (size_t)t*Cq;
  for (int h=0;h<Cq;h++){
    float a = w2[h];
    float xv[PTS];
    ld16(&xv[0],  &hidL[h*PTS+0]);  ld16(&xv[4],  &hidL[h*PTS+4]);
    ld16(&xv[8],  &hidL[h*PTS+8]);  ld16(&xv[12], &hidL[h*PTS+12]);
    #pragma unroll
    for (int p=0;p<PTS;p++) acc2[p]=fmaf(a,xv[p],acc2[p]);
  }
  float bsum = bv2[t] + bvs[t];
  #pragma unroll
  for (int p=0;p<PTS;p++){
    float v = acc2[p] + bsum;
    valL[t*PTS+p] = v;
    valueT[((size_t)(b*Nq + n0 + p))*Cq + t] = v;
  }
  __syncthreads();

  // kf/qf/vf projections: thread -> (o = t>>2, point-group pg_ = t&3)
  {
    const int o = t >> 2, pg_ = t & 3;
    float ak[4]={0,0,0,0}, aq[4]={0,0,0,0}, av[4]={0,0,0,0};
    const float* wkp = wk   + (size_t)o*Cq;
    const float* wqp = wq   + (size_t)o*Cq;
    const float* wvp = wval + (size_t)o*Cq;
    for (int c=0;c<Cq;c++){
      float a = wkp[c], bqw = wqp[c], cv = wvp[c];
      float xk[4], xq[4], xv[4];
      ld16(xk, &keyL[c*PTS + pg_*4]);
      ld16(xq, &qryL[c*PTS + pg_*4]);
      ld16(xv, &valL[c*PTS + pg_*4]);
      #pragma unroll
      for (int j=0;j<4;j++){
        ak[j]=fmaf(a,  xk[j],ak[j]);
        aq[j]=fmaf(bqw,xq[j],aq[j]);
        av[j]=fmaf(cv, xv[j],av[j]);
      }
    }
    float bko=bk[o], bqo=bq[o], bvo=bval[o];
    #pragma unroll
    for (int j=0;j<4;j++){
      int n = n0 + pg_*4 + j;
      kfT[((size_t)(b*Nq+n))*Dq + o] = ak[j]+bko;
      qfT[((size_t)(b*Nq+n))*Dq + o] = aq[j]+bqo;
      vfT[((size_t)(b*Nq+n))*Dq + o] = av[j]+bvo;
    }
  }
}

// ---------------------------------------------------------------------------
// Kernel 2: KNN (include_self). One block per (b,n). Exact-order fp32 dist
// (no contraction) + iterative argmin with lowest-index tie-break.
// ---------------------------------------------------------------------------
__global__ __launch_bounds__(256) void k_knn(const float* __restrict__ pos,
                                             int* __restrict__ idxT)
{
  __shared__ float dist[Nq];
  __shared__ float rmin[4];
  __shared__ int   rarg[4];
  const int t = threadIdx.x;
  const int b = blockIdx.x >> 11;
  const int n = blockIdx.x & (Nq-1);
  const float* px = pos + (size_t)(b*3+0)*Nq;
  const float* py = pos + (size_t)(b*3+1)*Nq;
  const float* pz = pos + (size_t)(b*3+2)*Nq;
  float xn=px[n], yn=py[n], zn=pz[n];
  float sqn = __fadd_rn(__fadd_rn(__fmul_rn(xn,xn),__fmul_rn(yn,yn)),__fmul_rn(zn,zn));
  for (int j=t;j<Nq;j+=256){
    float x=px[j], y=py[j], z=pz[j];
    float sqj = __fadd_rn(__fadd_rn(__fmul_rn(x,x),__fmul_rn(y,y)),__fmul_rn(z,z));
    float dot = __fadd_rn(__fadd_rn(__fmul_rn(xn,x),__fmul_rn(yn,y)),__fmul_rn(zn,z));
    dist[j] = __fsub_rn(__fadd_rn(sqn,sqj), __fmul_rn(2.0f,dot));
  }
  __syncthreads();
  for (int s=0;s<KNNq;s++){
    float best = 3.4e38f; int bi = Nq;
    for (int j=t;j<Nq;j+=256){
      float dv = dist[j];
      if (dv < best){ best=dv; bi=j; }   // ascending scan keeps lowest index on tie
    }
    #pragma unroll
    for (int off=32; off>0; off>>=1){
      float ob = __shfl_down(best, off);
      int   oi = __shfl_down(bi,  off);
      if (ob < best || (ob==best && oi<bi)){ best=ob; bi=oi; }
    }
    if ((t&63)==0){ rmin[t>>6]=best; rarg[t>>6]=bi; }
    __syncthreads();
    if (t==0){
      #pragma unroll
      for (int w=1;w<4;w++){
        if (rmin[w]<best || (rmin[w]==best && rarg[w]<bi)){ best=rmin[w]; bi=rarg[w]; }
      }
      idxT[((size_t)(b*Nq+n))*KNNq + s] = bi;
      dist[bi] = 3.4e38f;
    }
    __syncthreads();
  }
}

// ---------------------------------------------------------------------------
// Kernel 3: fused pos_mlp + attn_mlp + convT + softmax + aggregate + conv_end.
// One block (256 thr) per (b,n). Never materializes a/attn in global memory.
// ---------------------------------------------------------------------------
__global__ __launch_bounds__(256) void k_attn(
  const float* __restrict__ pos,
  const float* __restrict__ valueT, const float* __restrict__ kfT,
  const float* __restrict__ qfT,    const float* __restrict__ vfT,
  const int* __restrict__ idxT,
  const float* __restrict__ pw1, const float* __restrict__ pb1,
  const float* __restrict__ pg,  const float* __restrict__ pbt,
  const float* __restrict__ prm, const float* __restrict__ prv,
  const float* __restrict__ pw2, const float* __restrict__ pb2,
  const float* __restrict__ aw1, const float* __restrict__ ab1,
  const float* __restrict__ ag,  const float* __restrict__ abt,
  const float* __restrict__ arm, const float* __restrict__ arv,
  const float* __restrict__ ctw, const float* __restrict__ ctb,
  const float* __restrict__ we,  const float* __restrict__ be,
  float* __restrict__ out)
{
  __shared__ __align__(16) float u[Dq*KNNq];     // qk_rel + pos_emb
  __shared__ __align__(16) float vg[Dq*KNNq];    // v_g + pos_emb
  __shared__ __align__(16) float sS[DMq*KNNq];   // relu(bn(attn conv1))
  __shared__ __align__(16) float hS[PHq*KNNq];   // pos_mlp hidden
  __shared__ __align__(16) float aggS[Dq*UPq];
  __shared__ float prl[3*KNNq];
  __shared__ int   nb[KNNq];
  const int t = threadIdx.x;
  const int b = blockIdx.x >> 11;
  const int n = blockIdx.x & (Nq-1);

  if (t < KNNq){
    int j = idxT[((size_t)(b*Nq+n))*KNNq + t];
    nb[t] = j;
    #pragma unroll
    for (int d=0; d<3; d++){
      prl[d*KNNq+t] = pos[((size_t)(b*3+d))*Nq + n] - pos[((size_t)(b*3+d))*Nq + j];
    }
  }
  __syncthreads();

  // pos_mlp stage 1: h = relu(bn(pw1 * pos_rel + pb1)); thread -> (ph, kq)
  {
    const int ph = t & 63, kq = t >> 6;
    float sc = pg[ph] * rsqrtf(prv[ph] + 1e-5f);
    float sh = pbt[ph] - prm[ph] * sc;
    float w0 = pw1[ph*3+0], w1 = pw1[ph*3+1], w2 = pw1[ph*3+2];
    float bb = pb1[ph];
    #pragma unroll
    for (int m=0;m<5;m++){
      int k = kq + (m<<2);
      float h = w0*prl[k] + w1*prl[KNNq+k] + w2*prl[2*KNNq+k] + bb;
      hS[ph*KNNq+k] = fmaxf(h*sc + sh, 0.f);
    }
  }
  __syncthreads();

  // pos_emb + u (=qk_rel+pe) + vg (=v_g+pe); thread -> (o, kq)
  {
    const int o = t & 63, kq = t >> 6;
    float qv = qfT[((size_t)(b*Nq+n))*Dq + o];
    float pb = pb2[o];
    float acc[5];
    #pragma unroll
    for (int m=0;m<5;m++) acc[m]=pb;
    const float* w = pw2 + (size_t)o*PHq;
    for (int ph=0; ph<PHq; ph++){
      float wv = w[ph];
      #pragma unroll
      for (int m=0;m<5;m++) acc[m] = fmaf(wv, hS[ph*KNNq + kq + (m<<2)], acc[m]);
    }
    #pragma unroll
    for (int m=0;m<5;m++){
      int k = kq + (m<<2);
      int j = nb[k];
      float kg = kfT[((size_t)(b*Nq+j))*Dq + o];
      float vv = vfT[((size_t)(b*Nq+j))*Dq + o];
      u [o*KNNq+k] = (qv - kg) + acc[m];
      vg[o*KNNq+k] = vv + acc[m];
    }
  }
  __syncthreads();

  // attn conv1 (64 -> 256) + bn + relu; thread t = output channel c
  {
    float sc = ag[t] * rsqrtf(arv[t] + 1e-5f);
    float sh = abt[t] - arm[t] * sc;
    float bb = ab1[t];
    float acc[KNNq];
    #pragma unroll
    for (int k=0;k<KNNq;k++) acc[k]=0.f;
    const float* wa = aw1 + (size_t)t*Dq;
    for (int o=0;o<Dq;o++){
      float wv = wa[o];
      float uv[KNNq];
      #pragma unroll
      for (int q4=0;q4<5;q4++) ld16(&uv[q4*4], &u[o*KNNq + q4*4]);
      #pragma unroll
      for (int k=0;k<KNNq;k++) acc[k] = fmaf(wv, uv[k], acc[k]);
    }
    #pragma unroll
    for (int k=0;k<KNNq;k++)
      sS[t*KNNq+k] = fmaxf((acc[k]+bb)*sc + sh, 0.f);
  }
  __syncthreads();

  // ConvTranspose (256 -> 64x4) + softmax over k + aggregate; thread t=(o,r)
  {
    const int o = t >> 2;            // r = t & 3; ctw[c*256 + o*4 + r] = ctw[c*256 + t]
    float cb = ctb[o];
    float acc[KNNq];
    #pragma unroll
    for (int k=0;k<KNNq;k++) acc[k]=cb;
    for (int c=0;c<DMq;c++){
      float wv = ctw[(size_t)c*DMq + t];
      float sv[KNNq];
      #pragma unroll
      for (int q4=0;q4<5;q4++) ld16(&sv[q4*4], &sS[c*KNNq + q4*4]);
      #pragma unroll
      for (int k=0;k<KNNq;k++) acc[k] = fmaf(wv, sv[k], acc[k]);
    }
    float mx = acc[0];
    #pragma unroll
    for (int k=1;k<KNNq;k++) mx = fmaxf(mx, acc[k]);
    float sum = 0.f;
    #pragma unroll
    for (int k=0;k<KNNq;k++){ acc[k] = __expf(acc[k]-mx); sum += acc[k]; }
    float inv = 1.f/sum;
    float vv[KNNq];
    #pragma unroll
    for (int q4=0;q4<5;q4++) ld16(&vv[q4*4], &vg[o*KNNq + q4*4]);
    float a_ = 0.f;
    #pragma unroll
    for (int k=0;k<KNNq;k++) a_ = fmaf(acc[k]*inv, vv[k], a_);
    aggS[t] = a_;                    // aggS[o*4+r]
  }
  __syncthreads();

  // conv_end (64 -> 256) + bias + identity, write fp32; thread t = c
  {
    float y[4] = {0,0,0,0};
    const float* wep = we + (size_t)t*Dq;
    for (int o2=0;o2<Dq;o2++){
      float wv = wep[o2];
      float a4[4];
      ld16(a4, &aggS[o2*4]);
      #pragma unroll
      for (int j=0;j<4;j++) y[j]=fmaf(wv,a4[j],y[j]);
    }
    float bias = be[t] + valueT[((size_t)(b*Nq+n))*Cq + t];
    float4 o4;
    o4.x = y[0]+bias; o4.y = y[1]+bias; o4.z = y[2]+bias; o4.w = y[3]+bias;
    size_t ob = ((size_t)(b*Cq + t))*((size_t)Nq*UPq) + (size_t)n*UPq;
    *reinterpret_cast<float4*>(out + ob) = o4;
  }
}

// ---------------------------------------------------------------------------
extern "C" void kernel_launch(void* const* d_in, const int* in_sizes, int n_in,
                              void* d_out, int out_size, void* d_ws, size_t ws_size,
                              hipStream_t stream)
{
  const float* pos  = (const float*)d_in[0];
  const float* key  = (const float*)d_in[1];
  const float* qry  = (const float*)d_in[2];
  const float* wv1  = (const float*)d_in[3];
  const float* bv1  = (const float*)d_in[4];
  const float* wv2  = (const float*)d_in[5];
  const float* bv2  = (const float*)d_in[6];
  const float* wvs  = (const float*)d_in[7];
  const float* bvs  = (const float*)d_in[8];
  const float* wk   = (const float*)d_in[9];
  const float* bk   = (const float*)d_in[10];
  const float* wq   = (const float*)d_in[11];
  const float* bq   = (const float*)d_in[12];
  const float* wval = (const float*)d_in[13];
  const float* bval = (const float*)d_in[14];
  const float* pw1  = (const float*)d_in[15];
  const float* pb1  = (const float*)d_in[16];
  const float* pg   = (const float*)d_in[17];
  const float* pbt  = (const float*)d_in[18];
  const float* prm  = (const float*)d_in[19];
  const float* prv  = (const float*)d_in[20];
  const float* pw2  = (const float*)d_in[21];
  const float* pb2  = (const float*)d_in[22];
  const float* aw1  = (const float*)d_in[23];
  const float* ab1  = (const float*)d_in[24];
  const float* ag   = (const float*)d_in[25];
  const float* abt  = (const float*)d_in[26];
  const float* arm  = (const float*)d_in[27];
  const float* arv  = (const float*)d_in[28];
  const float* ctw  = (const float*)d_in[29];
  const float* ctb  = (const float*)d_in[30];
  const float* we   = (const float*)d_in[31];
  const float* be   = (const float*)d_in[32];

  char* ws = (char*)d_ws;
  float* valueT = (float*)(ws);                          // 2M floats = 8 MB
  float* kfT    = (float*)(ws + (size_t)8*1024*1024);    // 512K floats
  float* qfT    = (float*)(ws + (size_t)10*1024*1024);
  float* vfT    = (float*)(ws + (size_t)12*1024*1024);
  int*   idxT   = (int*)  (ws + (size_t)14*1024*1024);   // 160K ints
  float* out    = (float*)d_out;

  k_value<<<dim3(Bq*Nq/PTS), dim3(256), 0, stream>>>(
      key, qry, wv1, bv1, wv2, bv2, wvs, bvs, wk, bk, wq, bq, wval, bval,
      valueT, kfT, qfT, vfT);
  k_knn<<<dim3(Bq*Nq), dim3(256), 0, stream>>>(pos, idxT);
  k_attn<<<dim3(Bq*Nq), dim3(256), 0, stream>>>(
      pos, valueT, kfT, qfT, vfT, idxT,
      pw1, pb1, pg, pbt, prm, prv, pw2, pb2,
      aw1, ab1, ag, abt, arm, arv, ctw, ctb, we, be, out);
}

// Round 3
// 1041.271 us; speedup vs baseline: 1.0201x; 1.0201x over previous
//
#include <hip/hip_runtime.h>
#include <hip/hip_bf16.h>

#define Bq 4
#define Nq 2048
#define Cq 256
#define Dq 64
#define UPq 4
#define KNNq 20
#define PHq 64
#define DMq 256   // D*MULT
#define PTS 16    // points per block in k_value

typedef __attribute__((ext_vector_type(8))) short short8;
typedef __attribute__((ext_vector_type(4))) short short4v;
typedef __attribute__((ext_vector_type(4))) float f32x4;

__device__ __forceinline__ void ld16(float* d, const float* s){
  *reinterpret_cast<float4*>(d) = *reinterpret_cast<const float4*>(s);
}
__device__ __forceinline__ unsigned short f2b(float x){
  __hip_bfloat16 h = __float2bfloat16(x);
  return *reinterpret_cast<unsigned short*>(&h);
}
__device__ __forceinline__ float qmax4(float v){
  v = fmaxf(v, __shfl_xor(v,1)); v = fmaxf(v, __shfl_xor(v,2));
  v = fmaxf(v, __shfl_xor(v,4)); v = fmaxf(v, __shfl_xor(v,8));
  return v;
}
__device__ __forceinline__ float qsum4(float v){
  v += __shfl_xor(v,1); v += __shfl_xor(v,2);
  v += __shfl_xor(v,4); v += __shfl_xor(v,8);
  return v;
}

// ---------------------------------------------------------------------------
// Kernel 0: weight prep — bf16 conversions. aw1b[c][o] (as-is), ctwT[t][c]
// (transposed so convT GEMM's A operand is K-contiguous).
// ---------------------------------------------------------------------------
__global__ __launch_bounds__(256) void k_prep(
    const float* __restrict__ aw1, const float* __restrict__ ctw,
    short* __restrict__ aw1b, short* __restrict__ ctwT)
{
  const int t = threadIdx.x, bidx = blockIdx.x;
  if (bidx < 64){
    int i = bidx*256 + t;                 // 16384 elems
    aw1b[i] = (short)f2b(aw1[i]);
  } else {
    int c = bidx - 64;                    // 256 blocks
    ctwT[t*256 + c] = (short)f2b(ctw[c*256 + t]);
  }
}

// ---------------------------------------------------------------------------
// Kernel 1: value = MLP_Res(concat(key,query)); kf/qf/vf projections.
// (unchanged from round 2 — verified)
// ---------------------------------------------------------------------------
__global__ __launch_bounds__(256) void k_value(
    const float* __restrict__ key, const float* __restrict__ query,
    const float* __restrict__ wv1, const float* __restrict__ bv1,
    const float* __restrict__ wv2, const float* __restrict__ bv2,
    const float* __restrict__ wvs, const float* __restrict__ bvs,
    const float* __restrict__ wk,  const float* __restrict__ bk,
    const float* __restrict__ wq,  const float* __restrict__ bq,
    const float* __restrict__ wval,const float* __restrict__ bval,
    float* __restrict__ valueT, float* __restrict__ kfT,
    float* __restrict__ qfT,    float* __restrict__ vfT)
{
  __shared__ __align__(16) float keyL[Cq*PTS];
  __shared__ __align__(16) float qryL[Cq*PTS];
  __shared__ __align__(16) float hidL[Cq*PTS];
  __shared__ __align__(16) float valL[Cq*PTS];
  const int t  = threadIdx.x;
  const int blk = blockIdx.x;
  const int b  = blk >> 7;
  const int n0 = (blk & 127) * PTS;

  {
    const float* kp = key   + ((size_t)(b*Cq + t))*Nq + n0;
    const float* qp = query + ((size_t)(b*Cq + t))*Nq + n0;
    #pragma unroll
    for (int p=0;p<PTS;p+=4){
      ld16(&keyL[t*PTS+p], kp+p);
      ld16(&qryL[t*PTS+p], qp+p);
    }
  }
  __syncthreads();

  float acc1[PTS], acc2[PTS];
  #pragma unroll
  for (int p=0;p<PTS;p++){ acc1[p]=0.f; acc2[p]=0.f; }

  const float* w1  = wv1 + (size_t)t*(2*Cq);
  const float* wsp = wvs + (size_t)t*(2*Cq);
  for (int i=0;i<Cq;i++){
    float a = w1[i], s_ = wsp[i];
    float xv[PTS];
    ld16(&xv[0],  &keyL[i*PTS+0]);  ld16(&xv[4],  &keyL[i*PTS+4]);
    ld16(&xv[8],  &keyL[i*PTS+8]);  ld16(&xv[12], &keyL[i*PTS+12]);
    #pragma unroll
    for (int p=0;p<PTS;p++){ acc1[p]=fmaf(a,xv[p],acc1[p]); acc2[p]=fmaf(s_,xv[p],acc2[p]); }
  }
  for (int i=0;i<Cq;i++){
    float a = w1[Cq+i], s_ = wsp[Cq+i];
    float xv[PTS];
    ld16(&xv[0],  &qryL[i*PTS+0]);  ld16(&xv[4],  &qryL[i*PTS+4]);
    ld16(&xv[8],  &qryL[i*PTS+8]);  ld16(&xv[12], &qryL[i*PTS+12]);
    #pragma unroll
    for (int p=0;p<PTS;p++){ acc1[p]=fmaf(a,xv[p],acc1[p]); acc2[p]=fmaf(s_,xv[p],acc2[p]); }
  }
  float b1v = bv1[t];
  #pragma unroll
  for (int p=0;p<PTS;p++) hidL[t*PTS+p] = fmaxf(acc1[p]+b1v, 0.f);
  __syncthreads();

  const float* w2 = wv2 + (size_t)t*Cq;
  for (int h=0;h<Cq;h++){
    float a = w2[h];
    float xv[PTS];
    ld16(&xv[0],  &hidL[h*PTS+0]);  ld16(&xv[4],  &hidL[h*PTS+4]);
    ld16(&xv[8],  &hidL[h*PTS+8]);  ld16(&xv[12], &hidL[h*PTS+12]);
    #pragma unroll
    for (int p=0;p<PTS;p++) acc2[p]=fmaf(a,xv[p],acc2[p]);
  }
  float bsum = bv2[t] + bvs[t];
  #pragma unroll
  for (int p=0;p<PTS;p++){
    float v = acc2[p] + bsum;
    valL[t*PTS+p] = v;
    valueT[((size_t)(b*Nq + n0 + p))*Cq + t] = v;
  }
  __syncthreads();

  {
    const int o = t >> 2, pg_ = t & 3;
    float ak[4]={0,0,0,0}, aq[4]={0,0,0,0}, av[4]={0,0,0,0};
    const float* wkp = wk   + (size_t)o*Cq;
    const float* wqp = wq   + (size_t)o*Cq;
    const float* wvp = wval + (size_t)o*Cq;
    for (int c=0;c<Cq;c++){
      float a = wkp[c], bqw = wqp[c], cv = wvp[c];
      float xk[4], xq[4], xv[4];
      ld16(xk, &keyL[c*PTS + pg_*4]);
      ld16(xq, &qryL[c*PTS + pg_*4]);
      ld16(xv, &valL[c*PTS + pg_*4]);
      #pragma unroll
      for (int j=0;j<4;j++){
        ak[j]=fmaf(a,  xk[j],ak[j]);
        aq[j]=fmaf(bqw,xq[j],aq[j]);
        av[j]=fmaf(cv, xv[j],av[j]);
      }
    }
    float bko=bk[o], bqo=bq[o], bvo=bval[o];
    #pragma unroll
    for (int j=0;j<4;j++){
      int n = n0 + pg_*4 + j;
      kfT[((size_t)(b*Nq+n))*Dq + o] = ak[j]+bko;
      qfT[((size_t)(b*Nq+n))*Dq + o] = aq[j]+bqo;
      vfT[((size_t)(b*Nq+n))*Dq + o] = av[j]+bvo;
    }
  }
}

// ---------------------------------------------------------------------------
// Kernel 2: KNN — wave-per-point, distances in registers, no LDS/barriers.
// Lexicographic-successor scan over (d, j) reproduces argmin-with-removal
// (and jax top_k lowest-index tie-break) exactly.
// ---------------------------------------------------------------------------
__global__ __launch_bounds__(256) void k_knn(const float* __restrict__ pos,
                                             int* __restrict__ idxT)
{
  const int t = threadIdx.x;
  const int lane = t & 63;
  const int w = t >> 6;
  const int pid = blockIdx.x*4 + w;       // 2048 blocks * 4 waves = 8192 points
  const int b = pid >> 11;
  const int n = pid & (Nq-1);
  const float* px = pos + (size_t)(b*3+0)*Nq;
  const float* py = pos + (size_t)(b*3+1)*Nq;
  const float* pz = pos + (size_t)(b*3+2)*Nq;
  const float xn=px[n], yn=py[n], zn=pz[n];
  const float sqn = __fadd_rn(__fadd_rn(__fmul_rn(xn,xn),__fmul_rn(yn,yn)),__fmul_rn(zn,zn));

  float d[32];
  #pragma unroll
  for (int i=0;i<32;i++){
    int j = i*64 + lane;
    float x=px[j], y=py[j], z=pz[j];
    float sqj = __fadd_rn(__fadd_rn(__fmul_rn(x,x),__fmul_rn(y,y)),__fmul_rn(z,z));
    float dot = __fadd_rn(__fadd_rn(__fmul_rn(xn,x),__fmul_rn(yn,y)),__fmul_rn(zn,z));
    d[i] = __fsub_rn(__fadd_rn(sqn,sqj), __fmul_rn(2.0f,dot));
  }

  float last_d = -3.4e38f; int last_j = -1;
  for (int s=0;s<KNNq;s++){
    float best = 3.4e38f; int bj = 1<<30;
    #pragma unroll
    for (int i=0;i<32;i++){
      int j = i*64 + lane;
      float dv = d[i];
      bool valid = (dv > last_d) || (dv == last_d && j > last_j);
      if (valid && dv < best){ best = dv; bj = j; }   // within-lane ascending j keeps lowest on tie
    }
    #pragma unroll
    for (int off=1; off<64; off<<=1){
      float ob = __shfl_xor(best, off);
      int   oj = __shfl_xor(bj,  off);
      if (ob < best || (ob == best && oj < bj)){ best = ob; bj = oj; }
    }
    if (lane == 0) idxT[(size_t)pid*KNNq + s] = bj;
    last_d = best; last_j = bj;
  }
}

// ---------------------------------------------------------------------------
// Kernel 3: fused attn. pos_mlp/pos_emb/u-vg build = VALU (small); the two
// big GEMMs (conv1 64->256, convT 256->256) = bf16 MFMA 16x16x32.
// B operands staged in LDS as [n][K] bf16 (K-contiguous, padded rows);
// A operands (aw1b, ctwT) read straight from global (L1/L2-hot).
// Softmax over k done in-register on C-fragment layout with quad shuffles.
// ctb dropped: constant over k => cancels in softmax.
// ---------------------------------------------------------------------------
__global__ __launch_bounds__(256) void k_attn(
  const float* __restrict__ pos,
  const float* __restrict__ valueT, const float* __restrict__ kfT,
  const float* __restrict__ qfT,    const float* __restrict__ vfT,
  const int* __restrict__ idxT,
  const float* __restrict__ pw1, const float* __restrict__ pb1,
  const float* __restrict__ pg,  const float* __restrict__ pbt,
  const float* __restrict__ prm, const float* __restrict__ prv,
  const float* __restrict__ pw2, const float* __restrict__ pb2,
  const short* __restrict__ aw1b, const float* __restrict__ ab1,
  const float* __restrict__ ag,  const float* __restrict__ abt,
  const float* __restrict__ arm, const float* __restrict__ arv,
  const short* __restrict__ ctwT,
  const float* __restrict__ we,  const float* __restrict__ be,
  float* __restrict__ out)
{
  __shared__ __align__(16) float hS[PHq*KNNq];     // 5120 B
  __shared__ __align__(16) float vg[Dq*KNNq];      // 5120 B
  __shared__ __align__(16) short uT[32*72];        // 4608 B  B-layout [k][o], pad 72
  __shared__ __align__(16) short sT[32*264];       // 16896 B B-layout [k][c], pad 264
  __shared__ __align__(16) float aggS[DMq];        // 1024 B
  __shared__ float scS[DMq], sh2S[DMq];            // 2048 B
  __shared__ float prl[3*KNNq];
  __shared__ int   nb[KNNq];

  const int t = threadIdx.x;
  const int b = blockIdx.x >> 11;
  const int n = blockIdx.x & (Nq-1);
  const int lane = t & 63, quad = lane >> 4, l15 = lane & 15, w = t >> 6;

  // ---- stage 0: gather, bn coeffs, zero uT pad rows ----
  if (t < KNNq){
    int j = idxT[((size_t)(b*Nq+n))*KNNq + t];
    nb[t] = j;
    #pragma unroll
    for (int d=0; d<3; d++){
      prl[d*KNNq+t] = pos[((size_t)(b*3+d))*Nq + n] - pos[((size_t)(b*3+d))*Nq + j];
    }
  }
  {
    float sc = ag[t] * rsqrtf(arv[t] + 1e-5f);
    scS[t]  = sc;
    sh2S[t] = ab1[t]*sc + (abt[t] - arm[t]*sc);    // fold conv bias into bn shift
  }
  for (int i = 720 + t; i < 1152; i += 256) ((unsigned*)uT)[i] = 0u;  // rows 20..31
  __syncthreads();

  // ---- stage 1: pos_mlp hidden ----
  {
    const int ph = t & 63, kq = t >> 6;
    float sc = pg[ph] * rsqrtf(prv[ph] + 1e-5f);
    float sh = pbt[ph] - prm[ph] * sc;
    float w0 = pw1[ph*3+0], w1 = pw1[ph*3+1], w2 = pw1[ph*3+2];
    float bb = pb1[ph];
    #pragma unroll
    for (int m=0;m<5;m++){
      int k = kq + (m<<2);
      float h = w0*prl[k] + w1*prl[KNNq+k] + w2*prl[2*KNNq+k] + bb;
      hS[ph*KNNq+k] = fmaxf(h*sc + sh, 0.f);
    }
  }
  __syncthreads();

  // ---- stage 2: pos_emb + build uT (bf16, B-layout) and vg (fp32) ----
  {
    const int o = t & 63, kq = t >> 6;
    float qv = qfT[((size_t)(b*Nq+n))*Dq + o];
    float pb = pb2[o];
    float acc[5];
    #pragma unroll
    for (int m=0;m<5;m++) acc[m]=pb;
    const float* wp = pw2 + (size_t)o*PHq;
    for (int ph=0; ph<PHq; ph++){
      float wv = wp[ph];
      #pragma unroll
      for (int m=0;m<5;m++) acc[m] = fmaf(wv, hS[ph*KNNq + kq + (m<<2)], acc[m]);
    }
    #pragma unroll
    for (int m=0;m<5;m++){
      int k = kq + (m<<2);
      int j = nb[k];
      float kg = kfT[((size_t)(b*Nq+j))*Dq + o];
      float vv = vfT[((size_t)(b*Nq+j))*Dq + o];
      uT[k*72 + o]  = (short)f2b((qv - kg) + acc[m]);
      vg[o*KNNq+k]  = vv + acc[m];
    }
  }
  __syncthreads();

  // ---- stage 3: conv1 (64->256) via MFMA; epilogue bn+relu -> sT ----
  {
    f32x4 accC[4][2];
    #pragma unroll
    for (int jm=0;jm<4;jm++){ accC[jm][0]=(f32x4)0.f; accC[jm][1]=(f32x4)0.f; }
    #pragma unroll
    for (int ks=0;ks<2;ks++){
      const int kcol = ks*32 + quad*8;
      short8 b0 = *reinterpret_cast<const short8*>(&uT[ l15     *72 + kcol]);
      short8 b1 = *reinterpret_cast<const short8*>(&uT[(16+l15)*72 + kcol]);
      #pragma unroll
      for (int jm=0;jm<4;jm++){
        int mt = w*4 + jm;
        short8 a = *reinterpret_cast<const short8*>(aw1b + ((mt*16+l15)*64 + kcol));
        accC[jm][0] = __builtin_amdgcn_mfma_f32_16x16x32_bf16(a, b0, accC[jm][0], 0,0,0);
        accC[jm][1] = __builtin_amdgcn_mfma_f32_16x16x32_bf16(a, b1, accC[jm][1], 0,0,0);
      }
    }
    #pragma unroll
    for (int jm=0;jm<4;jm++){
      int mt = w*4 + jm;
      int cb = mt*16 + quad*4;
      #pragma unroll
      for (int nt=0;nt<2;nt++){
        int k = nt*16 + l15;
        short4v pk;
        #pragma unroll
        for (int r=0;r<4;r++){
          int c = cb + r;
          float s = fmaxf(accC[jm][nt][r]*scS[c] + sh2S[c], 0.f);
          pk[r] = (short)f2b(s);
        }
        *reinterpret_cast<short4v*>(&sT[k*264 + cb]) = pk;
      }
    }
  }
  __syncthreads();

  // ---- stage 4: convT (256->256) via MFMA + softmax + aggregate ----
  {
    f32x4 accT[4][2];
    #pragma unroll
    for (int jm=0;jm<4;jm++){ accT[jm][0]=(f32x4)0.f; accT[jm][1]=(f32x4)0.f; }
    #pragma unroll
    for (int ks=0;ks<8;ks++){
      const int kcol = ks*32 + quad*8;
      short8 b0 = *reinterpret_cast<const short8*>(&sT[ l15     *264 + kcol]);
      short8 b1 = *reinterpret_cast<const short8*>(&sT[(16+l15)*264 + kcol]);
      #pragma unroll
      for (int jm=0;jm<4;jm++){
        int mt = w*4 + jm;
        short8 a = *reinterpret_cast<const short8*>(ctwT + ((size_t)(mt*16+l15)*256 + kcol));
        accT[jm][0] = __builtin_amdgcn_mfma_f32_16x16x32_bf16(a, b0, accT[jm][0], 0,0,0);
        accT[jm][1] = __builtin_amdgcn_mfma_f32_16x16x32_bf16(a, b1, accT[jm][1], 0,0,0);
      }
    }
    const bool in1 = (l15 < 4);
    #pragma unroll
    for (int jm=0;jm<4;jm++){
      int mt = w*4 + jm;
      #pragma unroll
      for (int r=0;r<4;r++){
        int row = mt*16 + quad*4 + r;      // t_ = o*4 + rr
        int o = row >> 2;
        float v0 = accT[jm][0][r];
        float v1 = accT[jm][1][r];
        float m = qmax4(fmaxf(v0, in1 ? v1 : v0));
        float e0 = __expf(v0 - m);
        float e1 = in1 ? __expf(v1 - m) : 0.f;
        float ssum = qsum4(e0 + e1);
        float vg0 = vg[o*KNNq + l15];
        int i1 = in1 ? (o*KNNq + 16 + l15) : 0;
        float p = e0*vg0 + (in1 ? e1*vg[i1] : 0.f);
        float acc = qsum4(p);
        if (l15 == 0) aggS[row] = acc / ssum;
      }
    }
  }
  __syncthreads();

  // ---- stage 5: conv_end (64->256) + bias + identity ----
  {
    float y[4] = {0,0,0,0};
    const float* wep = we + (size_t)t*Dq;
    for (int o2=0;o2<Dq;o2++){
      float wv = wep[o2];
      float a4[4];
      ld16(a4, &aggS[o2*4]);
      #pragma unroll
      for (int j=0;j<4;j++) y[j]=fmaf(wv,a4[j],y[j]);
    }
    float bias = be[t] + valueT[((size_t)(b*Nq+n))*Cq + t];
    float4 o4;
    o4.x = y[0]+bias; o4.y = y[1]+bias; o4.z = y[2]+bias; o4.w = y[3]+bias;
    size_t ob = ((size_t)(b*Cq + t))*((size_t)Nq*UPq) + (size_t)n*UPq;
    *reinterpret_cast<float4*>(out + ob) = o4;
  }
}

// ---------------------------------------------------------------------------
extern "C" void kernel_launch(void* const* d_in, const int* in_sizes, int n_in,
                              void* d_out, int out_size, void* d_ws, size_t ws_size,
                              hipStream_t stream)
{
  const float* pos  = (const float*)d_in[0];
  const float* key  = (const float*)d_in[1];
  const float* qry  = (const float*)d_in[2];
  const float* wv1  = (const float*)d_in[3];
  const float* bv1  = (const float*)d_in[4];
  const float* wv2  = (const float*)d_in[5];
  const float* bv2  = (const float*)d_in[6];
  const float* wvs  = (const float*)d_in[7];
  const float* bvs  = (const float*)d_in[8];
  const float* wk   = (const float*)d_in[9];
  const float* bk   = (const float*)d_in[10];
  const float* wq   = (const float*)d_in[11];
  const float* bq   = (const float*)d_in[12];
  const float* wval = (const float*)d_in[13];
  const float* bval = (const float*)d_in[14];
  const float* pw1  = (const float*)d_in[15];
  const float* pb1  = (const float*)d_in[16];
  const float* pg   = (const float*)d_in[17];
  const float* pbt  = (const float*)d_in[18];
  const float* prm  = (const float*)d_in[19];
  const float* prv  = (const float*)d_in[20];
  const float* pw2  = (const float*)d_in[21];
  const float* pb2  = (const float*)d_in[22];
  const float* aw1  = (const float*)d_in[23];
  const float* ab1  = (const float*)d_in[24];
  const float* ag   = (const float*)d_in[25];
  const float* abt  = (const float*)d_in[26];
  const float* arm  = (const float*)d_in[27];
  const float* arv  = (const float*)d_in[28];
  const float* ctw  = (const float*)d_in[29];
  const float* we   = (const float*)d_in[31];
  const float* be   = (const float*)d_in[32];

  char* ws = (char*)d_ws;
  float* valueT = (float*)(ws);                          // 8 MB
  float* kfT    = (float*)(ws + (size_t)8*1024*1024);
  float* qfT    = (float*)(ws + (size_t)10*1024*1024);
  float* vfT    = (float*)(ws + (size_t)12*1024*1024);
  int*   idxT   = (int*)  (ws + (size_t)14*1024*1024);   // 640 KB
  short* aw1b   = (short*)(ws + (size_t)(14*1024+768)*1024);  // 32 KB
  short* ctwT   = (short*)(ws + (size_t)(14*1024+832)*1024);  // 128 KB
  float* out    = (float*)d_out;

  k_prep<<<dim3(320), dim3(256), 0, stream>>>(aw1, ctw, aw1b, ctwT);
  k_value<<<dim3(Bq*Nq/PTS), dim3(256), 0, stream>>>(
      key, qry, wv1, bv1, wv2, bv2, wvs, bvs, wk, bk, wq, bq, wval, bval,
      valueT, kfT, qfT, vfT);
  k_knn<<<dim3(Bq*Nq/4), dim3(256), 0, stream>>>(pos, idxT);
  k_attn<<<dim3(Bq*Nq), dim3(256), 0, stream>>>(
      pos, valueT, kfT, qfT, vfT, idxT,
      pw1, pb1, pg, pbt, prm, prv, pw2, pb2,
      aw1b, ab1, ag, abt, arm, arv, ctwT, we, be, out);
}

// Round 4
// 675.335 us; speedup vs baseline: 1.5728x; 1.5419x over previous
//
#include <hip/hip_runtime.h>
#include <hip/hip_bf16.h>

#define Bq 4
#define Nq 2048
#define Cq 256
#define Dq 64
#define UPq 4
#define KNNq 20
#define PHq 64
#define DMq 256   // D*MULT
#define PTS 16    // points per block in k_value

typedef __attribute__((ext_vector_type(8))) short short8;
typedef __attribute__((ext_vector_type(4))) short short4v;
typedef __attribute__((ext_vector_type(4))) float f32x4;
typedef __hip_bfloat16 bf16;

__device__ __forceinline__ void ld16(float* d, const float* s){
  *reinterpret_cast<float4*>(d) = *reinterpret_cast<const float4*>(s);
}
__device__ __forceinline__ unsigned short f2b(float x){
  bf16 h = __float2bfloat16(x);
  return *reinterpret_cast<unsigned short*>(&h);
}
__device__ __forceinline__ float b2f(short s){
  return __bfloat162float(*reinterpret_cast<bf16*>(&s));
}
__device__ __forceinline__ float qmax4(float v){
  v = fmaxf(v, __shfl_xor(v,1)); v = fmaxf(v, __shfl_xor(v,2));
  v = fmaxf(v, __shfl_xor(v,4)); v = fmaxf(v, __shfl_xor(v,8));
  return v;
}
__device__ __forceinline__ float qsum4(float v){
  v += __shfl_xor(v,1); v += __shfl_xor(v,2);
  v += __shfl_xor(v,4); v += __shfl_xor(v,8);
  return v;
}

// ---------------------------------------------------------------------------
// Kernel 0: weight prep — bf16 conversions for MFMA + fp32 transposes so
// every per-lane weight read in k_value/k_attn is coalesced.
// ---------------------------------------------------------------------------
__global__ __launch_bounds__(256) void k_prep(
    const float* __restrict__ aw1, const float* __restrict__ ctw,
    const float* __restrict__ wv1, const float* __restrict__ wvs,
    const float* __restrict__ wv2, const float* __restrict__ wk,
    const float* __restrict__ wq,  const float* __restrict__ wval,
    const float* __restrict__ pw2, const float* __restrict__ we,
    short* __restrict__ aw1b, short* __restrict__ ctwT,
    float* __restrict__ wv1T, float* __restrict__ wvsT,
    float* __restrict__ wv2T, float* __restrict__ wkT,
    float* __restrict__ wqT,  float* __restrict__ wvalT,
    float* __restrict__ pw2T, float* __restrict__ weT)
{
  const int t = threadIdx.x, bidx = blockIdx.x;
  if (bidx < 64){                                  // aw1b: bf16 copy (256x64)
    int i = bidx*256 + t;
    aw1b[i] = (short)f2b(aw1[i]);
  } else if (bidx < 320){                          // ctwT[t][c] = ctw[c][t]
    int c = bidx - 64;
    ctwT[t*256 + c] = (short)f2b(ctw[c*256 + t]);
  } else if (bidx < 832){                          // wv1T[i][o], i<512, o<256
    int i = bidx - 320;
    wv1T[i*256 + t] = wv1[t*512 + i];
  } else if (bidx < 1344){                         // wvsT[i][o]
    int i = bidx - 832;
    wvsT[i*256 + t] = wvs[t*512 + i];
  } else if (bidx < 1600){                         // wv2T[h][o], 256x256
    int h = bidx - 1344;
    wv2T[h*256 + t] = wv2[t*256 + h];
  } else if (bidx < 1664){                         // wkT[c][o], 256x64
    int l = (bidx-1600)*256 + t; int c = l>>6, o = l&63;
    wkT[c*64+o] = wk[o*256+c];
  } else if (bidx < 1728){
    int l = (bidx-1664)*256 + t; int c = l>>6, o = l&63;
    wqT[c*64+o] = wq[o*256+c];
  } else if (bidx < 1792){
    int l = (bidx-1728)*256 + t; int c = l>>6, o = l&63;
    wvalT[c*64+o] = wval[o*256+c];
  } else if (bidx < 1808){                         // pw2T[ph][o], 64x64
    int l = (bidx-1792)*256 + t; int ph = l>>6, o = l&63;
    pw2T[ph*64+o] = pw2[o*64+ph];
  } else {                                         // weT[o2][c], 64x256
    int l = (bidx-1808)*256 + t; int o2 = l>>8, c = l&255;
    weT[o2*256+c] = we[c*64+o2];
  }
}

// ---------------------------------------------------------------------------
// Kernel 1: value = MLP_Res(concat(key,query)); kf/qf/vf projections.
// All weight reads coalesced via transposed copies.
// ---------------------------------------------------------------------------
__global__ __launch_bounds__(256) void k_value(
    const float* __restrict__ key, const float* __restrict__ query,
    const float* __restrict__ wv1T, const float* __restrict__ bv1,
    const float* __restrict__ wv2T, const float* __restrict__ bv2,
    const float* __restrict__ wvsT, const float* __restrict__ bvs,
    const float* __restrict__ wkT,  const float* __restrict__ bk,
    const float* __restrict__ wqT,  const float* __restrict__ bq,
    const float* __restrict__ wvalT,const float* __restrict__ bval,
    float* __restrict__ valueT, short* __restrict__ kfT,
    short* __restrict__ qfT,    short* __restrict__ vfT)
{
  __shared__ __align__(16) float keyL[Cq*PTS];
  __shared__ __align__(16) float qryL[Cq*PTS];
  __shared__ __align__(16) float hidL[Cq*PTS];
  __shared__ __align__(16) float valL[Cq*PTS];
  const int t  = threadIdx.x;
  const int blk = blockIdx.x;
  const int b  = blk >> 7;
  const int n0 = (blk & 127) * PTS;

  {
    const float* kp = key   + ((size_t)(b*Cq + t))*Nq + n0;
    const float* qp = query + ((size_t)(b*Cq + t))*Nq + n0;
    #pragma unroll
    for (int p=0;p<PTS;p+=4){
      ld16(&keyL[t*PTS+p], kp+p);
      ld16(&qryL[t*PTS+p], qp+p);
    }
  }
  __syncthreads();

  float acc1[PTS], acc2[PTS];
  #pragma unroll
  for (int p=0;p<PTS;p++){ acc1[p]=0.f; acc2[p]=0.f; }

  for (int i=0;i<Cq;i++){
    float a = wv1T[i*256 + t], s_ = wvsT[i*256 + t];
    float xv[PTS];
    ld16(&xv[0],  &keyL[i*PTS+0]);  ld16(&xv[4],  &keyL[i*PTS+4]);
    ld16(&xv[8],  &keyL[i*PTS+8]);  ld16(&xv[12], &keyL[i*PTS+12]);
    #pragma unroll
    for (int p=0;p<PTS;p++){ acc1[p]=fmaf(a,xv[p],acc1[p]); acc2[p]=fmaf(s_,xv[p],acc2[p]); }
  }
  for (int i=0;i<Cq;i++){
    float a = wv1T[(Cq+i)*256 + t], s_ = wvsT[(Cq+i)*256 + t];
    float xv[PTS];
    ld16(&xv[0],  &qryL[i*PTS+0]);  ld16(&xv[4],  &qryL[i*PTS+4]);
    ld16(&xv[8],  &qryL[i*PTS+8]);  ld16(&xv[12], &qryL[i*PTS+12]);
    #pragma unroll
    for (int p=0;p<PTS;p++){ acc1[p]=fmaf(a,xv[p],acc1[p]); acc2[p]=fmaf(s_,xv[p],acc2[p]); }
  }
  float b1v = bv1[t];
  #pragma unroll
  for (int p=0;p<PTS;p++) hidL[t*PTS+p] = fmaxf(acc1[p]+b1v, 0.f);
  __syncthreads();

  for (int h=0;h<Cq;h++){
    float a = wv2T[h*256 + t];
    float xv[PTS];
    ld16(&xv[0],  &hidL[h*PTS+0]);  ld16(&xv[4],  &hidL[h*PTS+4]);
    ld16(&xv[8],  &hidL[h*PTS+8]);  ld16(&xv[12], &hidL[h*PTS+12]);
    #pragma unroll
    for (int p=0;p<PTS;p++) acc2[p]=fmaf(a,xv[p],acc2[p]);
  }
  float bsum = bv2[t] + bvs[t];
  #pragma unroll
  for (int p=0;p<PTS;p++){
    float v = acc2[p] + bsum;
    valL[t*PTS+p] = v;
    valueT[((size_t)(b*Nq + n0 + p))*Cq + t] = v;
  }
  __syncthreads();

  {
    const int o = t >> 2, pg_ = t & 3;
    float ak[4]={0,0,0,0}, aq[4]={0,0,0,0}, av[4]={0,0,0,0};
    for (int c=0;c<Cq;c++){
      float a = wkT[c*64+o], bqw = wqT[c*64+o], cv = wvalT[c*64+o];
      float xk[4], xq[4], xv[4];
      ld16(xk, &keyL[c*PTS + pg_*4]);
      ld16(xq, &qryL[c*PTS + pg_*4]);
      ld16(xv, &valL[c*PTS + pg_*4]);
      #pragma unroll
      for (int j=0;j<4;j++){
        ak[j]=fmaf(a,  xk[j],ak[j]);
        aq[j]=fmaf(bqw,xq[j],aq[j]);
        av[j]=fmaf(cv, xv[j],av[j]);
      }
    }
    float bko=bk[o], bqo=bq[o], bvo=bval[o];
    #pragma unroll
    for (int j=0;j<4;j++){
      int n = n0 + pg_*4 + j;
      kfT[((size_t)(b*Nq+n))*Dq + o] = (short)f2b(ak[j]+bko);
      qfT[((size_t)(b*Nq+n))*Dq + o] = (short)f2b(aq[j]+bqo);
      vfT[((size_t)(b*Nq+n))*Dq + o] = (short)f2b(av[j]+bvo);
    }
  }
}

// ---------------------------------------------------------------------------
// Kernel 2: KNN — wave-per-point, distances in registers (unchanged).
// ---------------------------------------------------------------------------
__global__ __launch_bounds__(256) void k_knn(const float* __restrict__ pos,
                                             int* __restrict__ idxT)
{
  const int t = threadIdx.x;
  const int lane = t & 63;
  const int w = t >> 6;
  const int pid = blockIdx.x*4 + w;
  const int b = pid >> 11;
  const int n = pid & (Nq-1);
  const float* px = pos + (size_t)(b*3+0)*Nq;
  const float* py = pos + (size_t)(b*3+1)*Nq;
  const float* pz = pos + (size_t)(b*3+2)*Nq;
  const float xn=px[n], yn=py[n], zn=pz[n];
  const float sqn = __fadd_rn(__fadd_rn(__fmul_rn(xn,xn),__fmul_rn(yn,yn)),__fmul_rn(zn,zn));

  float d[32];
  #pragma unroll
  for (int i=0;i<32;i++){
    int j = i*64 + lane;
    float x=px[j], y=py[j], z=pz[j];
    float sqj = __fadd_rn(__fadd_rn(__fmul_rn(x,x),__fmul_rn(y,y)),__fmul_rn(z,z));
    float dot = __fadd_rn(__fadd_rn(__fmul_rn(xn,x),__fmul_rn(yn,y)),__fmul_rn(zn,z));
    d[i] = __fsub_rn(__fadd_rn(sqn,sqj), __fmul_rn(2.0f,dot));
  }

  float last_d = -3.4e38f; int last_j = -1;
  for (int s=0;s<KNNq;s++){
    float best = 3.4e38f; int bj = 1<<30;
    #pragma unroll
    for (int i=0;i<32;i++){
      int j = i*64 + lane;
      float dv = d[i];
      bool valid = (dv > last_d) || (dv == last_d && j > last_j);
      if (valid && dv < best){ best = dv; bj = j; }
    }
    #pragma unroll
    for (int off=1; off<64; off<<=1){
      float ob = __shfl_xor(best, off);
      int   oj = __shfl_xor(bj,  off);
      if (ob < best || (ob == best && oj < bj)){ best = ob; bj = oj; }
    }
    if (lane == 0) idxT[(size_t)pid*KNNq + s] = bj;
    last_d = best; last_j = bj;
  }
}

// ---------------------------------------------------------------------------
// Kernel 3: fused attn (MFMA GEMMs + in-register softmax). pw2/we reads now
// coalesced via transposes; kf/qf/vf gathers in bf16.
// ---------------------------------------------------------------------------
__global__ __launch_bounds__(256) void k_attn(
  const float* __restrict__ pos,
  const float* __restrict__ valueT, const short* __restrict__ kfT,
  const short* __restrict__ qfT,    const short* __restrict__ vfT,
  const int* __restrict__ idxT,
  const float* __restrict__ pw1, const float* __restrict__ pb1,
  const float* __restrict__ pg,  const float* __restrict__ pbt,
  const float* __restrict__ prm, const float* __restrict__ prv,
  const float* __restrict__ pw2T, const float* __restrict__ pb2,
  const short* __restrict__ aw1b, const float* __restrict__ ab1,
  const float* __restrict__ ag,  const float* __restrict__ abt,
  const float* __restrict__ arm, const float* __restrict__ arv,
  const short* __restrict__ ctwT,
  const float* __restrict__ weT,  const float* __restrict__ be,
  float* __restrict__ out)
{
  __shared__ __align__(16) float hS[PHq*KNNq];
  __shared__ __align__(16) float vg[Dq*KNNq];
  __shared__ __align__(16) short uT[32*72];
  __shared__ __align__(16) short sT[32*264];
  __shared__ __align__(16) float aggS[DMq];
  __shared__ float scS[DMq], sh2S[DMq];
  __shared__ float prl[3*KNNq];
  __shared__ int   nb[KNNq];

  const int t = threadIdx.x;
  const int b = blockIdx.x >> 11;
  const int n = blockIdx.x & (Nq-1);
  const int lane = t & 63, quad = lane >> 4, l15 = lane & 15, w = t >> 6;

  if (t < KNNq){
    int j = idxT[((size_t)(b*Nq+n))*KNNq + t];
    nb[t] = j;
    #pragma unroll
    for (int d=0; d<3; d++){
      prl[d*KNNq+t] = pos[((size_t)(b*3+d))*Nq + n] - pos[((size_t)(b*3+d))*Nq + j];
    }
  }
  {
    float sc = ag[t] * rsqrtf(arv[t] + 1e-5f);
    scS[t]  = sc;
    sh2S[t] = ab1[t]*sc + (abt[t] - arm[t]*sc);
  }
  for (int i = 720 + t; i < 1152; i += 256) ((unsigned*)uT)[i] = 0u;
  __syncthreads();

  // ---- stage 1: pos_mlp hidden ----
  {
    const int ph = t & 63, kq = t >> 6;
    float sc = pg[ph] * rsqrtf(prv[ph] + 1e-5f);
    float sh = pbt[ph] - prm[ph] * sc;
    float w0 = pw1[ph*3+0], w1 = pw1[ph*3+1], w2 = pw1[ph*3+2];
    float bb = pb1[ph];
    #pragma unroll
    for (int m=0;m<5;m++){
      int k = kq + (m<<2);
      float h = w0*prl[k] + w1*prl[KNNq+k] + w2*prl[2*KNNq+k] + bb;
      hS[ph*KNNq+k] = fmaxf(h*sc + sh, 0.f);
    }
  }
  __syncthreads();

  // ---- stage 2: pos_emb + build uT (bf16) and vg (fp32) ----
  {
    const int o = t & 63, kq = t >> 6;
    float qv = b2f(qfT[((size_t)(b*Nq+n))*Dq + o]);
    float pb = pb2[o];
    float acc[5];
    #pragma unroll
    for (int m=0;m<5;m++) acc[m]=pb;
    for (int ph=0; ph<PHq; ph++){
      float wv = pw2T[ph*64 + o];
      #pragma unroll
      for (int m=0;m<5;m++) acc[m] = fmaf(wv, hS[ph*KNNq + kq + (m<<2)], acc[m]);
    }
    #pragma unroll
    for (int m=0;m<5;m++){
      int k = kq + (m<<2);
      int j = nb[k];
      float kg = b2f(kfT[((size_t)(b*Nq+j))*Dq + o]);
      float vv = b2f(vfT[((size_t)(b*Nq+j))*Dq + o]);
      uT[k*72 + o]  = (short)f2b((qv - kg) + acc[m]);
      vg[o*KNNq+k]  = vv + acc[m];
    }
  }
  __syncthreads();

  // ---- stage 3: conv1 (64->256) via MFMA; epilogue bn+relu -> sT ----
  {
    f32x4 accC[4][2];
    #pragma unroll
    for (int jm=0;jm<4;jm++){ accC[jm][0]=(f32x4)0.f; accC[jm][1]=(f32x4)0.f; }
    #pragma unroll
    for (int ks=0;ks<2;ks++){
      const int kcol = ks*32 + quad*8;
      short8 b0 = *reinterpret_cast<const short8*>(&uT[ l15     *72 + kcol]);
      short8 b1 = *reinterpret_cast<const short8*>(&uT[(16+l15)*72 + kcol]);
      #pragma unroll
      for (int jm=0;jm<4;jm++){
        int mt = w*4 + jm;
        short8 a = *reinterpret_cast<const short8*>(aw1b + ((mt*16+l15)*64 + kcol));
        accC[jm][0] = __builtin_amdgcn_mfma_f32_16x16x32_bf16(a, b0, accC[jm][0], 0,0,0);
        accC[jm][1] = __builtin_amdgcn_mfma_f32_16x16x32_bf16(a, b1, accC[jm][1], 0,0,0);
      }
    }
    #pragma unroll
    for (int jm=0;jm<4;jm++){
      int mt = w*4 + jm;
      int cb = mt*16 + quad*4;
      #pragma unroll
      for (int nt=0;nt<2;nt++){
        int k = nt*16 + l15;
        short4v pk;
        #pragma unroll
        for (int r=0;r<4;r++){
          int c = cb + r;
          float s = fmaxf(accC[jm][nt][r]*scS[c] + sh2S[c], 0.f);
          pk[r] = (short)f2b(s);
        }
        *reinterpret_cast<short4v*>(&sT[k*264 + cb]) = pk;
      }
    }
  }
  __syncthreads();

  // ---- stage 4: convT (256->256) via MFMA + softmax + aggregate ----
  {
    f32x4 accT[4][2];
    #pragma unroll
    for (int jm=0;jm<4;jm++){ accT[jm][0]=(f32x4)0.f; accT[jm][1]=(f32x4)0.f; }
    #pragma unroll
    for (int ks=0;ks<8;ks++){
      const int kcol = ks*32 + quad*8;
      short8 b0 = *reinterpret_cast<const short8*>(&sT[ l15     *264 + kcol]);
      short8 b1 = *reinterpret_cast<const short8*>(&sT[(16+l15)*264 + kcol]);
      #pragma unroll
      for (int jm=0;jm<4;jm++){
        int mt = w*4 + jm;
        short8 a = *reinterpret_cast<const short8*>(ctwT + ((size_t)(mt*16+l15)*256 + kcol));
        accT[jm][0] = __builtin_amdgcn_mfma_f32_16x16x32_bf16(a, b0, accT[jm][0], 0,0,0);
        accT[jm][1] = __builtin_amdgcn_mfma_f32_16x16x32_bf16(a, b1, accT[jm][1], 0,0,0);
      }
    }
    const bool in1 = (l15 < 4);
    #pragma unroll
    for (int jm=0;jm<4;jm++){
      int mt = w*4 + jm;
      #pragma unroll
      for (int r=0;r<4;r++){
        int row = mt*16 + quad*4 + r;
        int o = row >> 2;
        float v0 = accT[jm][0][r];
        float v1 = accT[jm][1][r];
        float m = qmax4(fmaxf(v0, in1 ? v1 : v0));
        float e0 = __expf(v0 - m);
        float e1 = in1 ? __expf(v1 - m) : 0.f;
        float ssum = qsum4(e0 + e1);
        float vg0 = vg[o*KNNq + l15];
        int i1 = in1 ? (o*KNNq + 16 + l15) : 0;
        float p = e0*vg0 + (in1 ? e1*vg[i1] : 0.f);
        float acc = qsum4(p);
        if (l15 == 0) aggS[row] = acc / ssum;
      }
    }
  }
  __syncthreads();

  // ---- stage 5: conv_end (64->256) + bias + identity ----
  {
    float y[4] = {0,0,0,0};
    for (int o2=0;o2<Dq;o2++){
      float wv = weT[o2*256 + t];
      float a4[4];
      ld16(a4, &aggS[o2*4]);
      #pragma unroll
      for (int j=0;j<4;j++) y[j]=fmaf(wv,a4[j],y[j]);
    }
    float bias = be[t] + valueT[((size_t)(b*Nq+n))*Cq + t];
    float4 o4;
    o4.x = y[0]+bias; o4.y = y[1]+bias; o4.z = y[2]+bias; o4.w = y[3]+bias;
    size_t ob = ((size_t)(b*Cq + t))*((size_t)Nq*UPq) + (size_t)n*UPq;
    *reinterpret_cast<float4*>(out + ob) = o4;
  }
}

// ---------------------------------------------------------------------------
extern "C" void kernel_launch(void* const* d_in, const int* in_sizes, int n_in,
                              void* d_out, int out_size, void* d_ws, size_t ws_size,
                              hipStream_t stream)
{
  const float* pos  = (const float*)d_in[0];
  const float* key  = (const float*)d_in[1];
  const float* qry  = (const float*)d_in[2];
  const float* wv1  = (const float*)d_in[3];
  const float* bv1  = (const float*)d_in[4];
  const float* wv2  = (const float*)d_in[5];
  const float* bv2  = (const float*)d_in[6];
  const float* wvs  = (const float*)d_in[7];
  const float* bvs  = (const float*)d_in[8];
  const float* wk   = (const float*)d_in[9];
  const float* bk   = (const float*)d_in[10];
  const float* wq   = (const float*)d_in[11];
  const float* bq   = (const float*)d_in[12];
  const float* wval = (const float*)d_in[13];
  const float* bval = (const float*)d_in[14];
  const float* pw1  = (const float*)d_in[15];
  const float* pb1  = (const float*)d_in[16];
  const float* pg   = (const float*)d_in[17];
  const float* pbt  = (const float*)d_in[18];
  const float* prm  = (const float*)d_in[19];
  const float* prv  = (const float*)d_in[20];
  const float* pw2  = (const float*)d_in[21];
  const float* pb2  = (const float*)d_in[22];
  const float* aw1  = (const float*)d_in[23];
  const float* ab1  = (const float*)d_in[24];
  const float* ag   = (const float*)d_in[25];
  const float* abt  = (const float*)d_in[26];
  const float* arm  = (const float*)d_in[27];
  const float* arv  = (const float*)d_in[28];
  const float* ctw  = (const float*)d_in[29];
  const float* we   = (const float*)d_in[31];
  const float* be   = (const float*)d_in[32];

  char* ws = (char*)d_ws;
  float* valueT = (float*)(ws);                              // 8 MB fp32
  short* kfT    = (short*)(ws + 8388608);                    // 1 MB bf16
  short* qfT    = (short*)(ws + 9437184);
  short* vfT    = (short*)(ws + 10485760);
  int*   idxT   = (int*)  (ws + 11534336);                   // 640 KB
  short* aw1b   = (short*)(ws + 12189696);                   // 32 KB
  short* ctwT   = (short*)(ws + 12222464);                   // 128 KB
  float* wv1T   = (float*)(ws + 12353536);                   // 512 KB
  float* wvsT   = (float*)(ws + 12877824);                   // 512 KB
  float* wv2T   = (float*)(ws + 13402112);                   // 256 KB
  float* wkT    = (float*)(ws + 13664256);                   // 64 KB
  float* wqT    = (float*)(ws + 13729792);
  float* wvalT  = (float*)(ws + 13795328);
  float* pw2T   = (float*)(ws + 13860864);                   // 16 KB
  float* weT    = (float*)(ws + 13877248);                   // 64 KB
  float* out    = (float*)d_out;

  k_prep<<<dim3(1872), dim3(256), 0, stream>>>(
      aw1, ctw, wv1, wvs, wv2, wk, wq, wval, pw2, we,
      aw1b, ctwT, wv1T, wvsT, wv2T, wkT, wqT, wvalT, pw2T, weT);
  k_value<<<dim3(Bq*Nq/PTS), dim3(256), 0, stream>>>(
      key, qry, wv1T, bv1, wv2T, bv2, wvsT, bvs, wkT, bk, wqT, bq, wvalT, bval,
      valueT, kfT, qfT, vfT);
  k_knn<<<dim3(Bq*Nq/4), dim3(256), 0, stream>>>(pos, idxT);
  k_attn<<<dim3(Bq*Nq), dim3(256), 0, stream>>>(
      pos, valueT, kfT, qfT, vfT, idxT,
      pw1, pb1, pg, pbt, prm, prv, pw2T, pb2,
      aw1b, ab1, ag, abt, arm, arv, ctwT, weT, be, out);
}

// Round 5
// 585.997 us; speedup vs baseline: 1.8126x; 1.1525x over previous
//
#include <hip/hip_runtime.h>
#include <hip/hip_bf16.h>

#define Bq 4
#define Nq 2048
#define Cq 256
#define Dq 64
#define UPq 4
#define KNNq 20
#define PHq 64
#define DMq 256   // D*MULT
#define PTS 16    // points per block in k_value

typedef __attribute__((ext_vector_type(8))) short short8;
typedef __attribute__((ext_vector_type(4))) short short4v;
typedef __attribute__((ext_vector_type(4))) float f32x4;
typedef __hip_bfloat16 bf16;

__device__ __forceinline__ void ld16(float* d, const float* s){
  *reinterpret_cast<float4*>(d) = *reinterpret_cast<const float4*>(s);
}
__device__ __forceinline__ unsigned short f2b(float x){
  bf16 h = __float2bfloat16(x);
  return *reinterpret_cast<unsigned short*>(&h);
}
__device__ __forceinline__ float b2f(short s){
  return __bfloat162float(*reinterpret_cast<bf16*>(&s));
}
__device__ __forceinline__ float qmax4(float v){
  v = fmaxf(v, __shfl_xor(v,1)); v = fmaxf(v, __shfl_xor(v,2));
  v = fmaxf(v, __shfl_xor(v,4)); v = fmaxf(v, __shfl_xor(v,8));
  return v;
}
__device__ __forceinline__ float qsum4(float v){
  v += __shfl_xor(v,1); v += __shfl_xor(v,2);
  v += __shfl_xor(v,4); v += __shfl_xor(v,8);
  return v;
}

// ---------------------------------------------------------------------------
// Kernel 0: weight prep — bf16 conversions (row-major, coalesced both sides
// except the two small transposes ctwT/pw2T/weT).
// ---------------------------------------------------------------------------
__global__ __launch_bounds__(256) void k_prep(
    const float* __restrict__ aw1, const float* __restrict__ ctw,
    const float* __restrict__ wv1, const float* __restrict__ wvs,
    const float* __restrict__ wv2, const float* __restrict__ wk,
    const float* __restrict__ wq,  const float* __restrict__ wval,
    const float* __restrict__ pw2, const float* __restrict__ we,
    short* __restrict__ aw1b, short* __restrict__ ctwT,
    short* __restrict__ wv1b, short* __restrict__ wvsb,
    short* __restrict__ wv2b, short* __restrict__ wkb,
    short* __restrict__ wqb,  short* __restrict__ wvalb,
    float* __restrict__ pw2T, float* __restrict__ weT)
{
  const int t = threadIdx.x, bidx = blockIdx.x;
  if (bidx < 64){                                  // aw1b 256x64 bf16
    int i = bidx*256 + t;
    aw1b[i] = (short)f2b(aw1[i]);
  } else if (bidx < 320){                          // ctwT[t][c] = ctw[c][t]
    int c = bidx - 64;
    ctwT[t*256 + c] = (short)f2b(ctw[c*256 + t]);
  } else if (bidx < 832){                          // wv1b straight 256x512
    int i = (bidx-320)*256 + t;
    wv1b[i] = (short)f2b(wv1[i]);
  } else if (bidx < 1344){                         // wvsb straight
    int i = (bidx-832)*256 + t;
    wvsb[i] = (short)f2b(wvs[i]);
  } else if (bidx < 1600){                         // wv2b straight 256x256
    int i = (bidx-1344)*256 + t;
    wv2b[i] = (short)f2b(wv2[i]);
  } else if (bidx < 1664){                         // wkb straight 64x256
    int i = (bidx-1600)*256 + t;
    wkb[i] = (short)f2b(wk[i]);
  } else if (bidx < 1728){
    int i = (bidx-1664)*256 + t;
    wqb[i] = (short)f2b(wq[i]);
  } else if (bidx < 1792){
    int i = (bidx-1728)*256 + t;
    wvalb[i] = (short)f2b(wval[i]);
  } else if (bidx < 1808){                         // pw2T[ph][o] fp32 64x64
    int l = (bidx-1792)*256 + t; int ph = l>>6, o = l&63;
    pw2T[ph*64+o] = pw2[o*64+ph];
  } else {                                         // weT[o2][c] fp32 64x256
    int l = (bidx-1808)*256 + t; int o2 = l>>8, c = l&255;
    weT[o2*256+c] = we[c*64+o2];
  }
}

// ---------------------------------------------------------------------------
// Kernel 1: value MLP + projections, fully MFMA (bf16 in, fp32 acc).
// Block = 16 points; X = concat(key,query) staged as B-tile [n][K] in LDS.
// conv1+shortcut: 128 MFMA/wave; wv2 accumulates into shortcut acc: 32;
// k/q/v projections: 24. Epilogues write hid/val back as bf16 B-tiles.
// ---------------------------------------------------------------------------
__global__ __launch_bounds__(256) void k_value(
    const float* __restrict__ key, const float* __restrict__ query,
    const short* __restrict__ wv1b, const short* __restrict__ wvsb,
    const short* __restrict__ wv2b, const short* __restrict__ wkb,
    const short* __restrict__ wqb,  const short* __restrict__ wvalb,
    const float* __restrict__ bv1, const float* __restrict__ bv2,
    const float* __restrict__ bvs, const float* __restrict__ bk,
    const float* __restrict__ bq,  const float* __restrict__ bval,
    float* __restrict__ valueT, short* __restrict__ kfT,
    short* __restrict__ qfT,    short* __restrict__ vfT)
{
  __shared__ __align__(16) short Xb[16*520];    // [n][k<512], stride 520
  __shared__ __align__(16) short hidB[16*264];  // [n][h<256], stride 264
  __shared__ __align__(16) short valB[16*264];  // [n][c<256] bf16
  __shared__ __align__(16) float valF[16*264];  // [n][c<256] fp32
  const int t = threadIdx.x;
  const int b = blockIdx.x >> 7;
  const int n0 = (blockIdx.x & 127) * PTS;
  const int lane = t & 63, quad = lane >> 4, l15 = lane & 15, w = t >> 6;

  // stage X^T (bf16) into LDS; thread t = input channel
  {
    const float* kp = key   + ((size_t)(b*Cq + t))*Nq + n0;
    const float* qp = query + ((size_t)(b*Cq + t))*Nq + n0;
    float kv[16], qv[16];
    #pragma unroll
    for (int p=0;p<PTS;p+=4){ ld16(&kv[p], kp+p); ld16(&qv[p], qp+p); }
    #pragma unroll
    for (int p=0;p<PTS;p++){
      Xb[p*520 + t]       = (short)f2b(kv[p]);
      Xb[p*520 + 256 + t] = (short)f2b(qv[p]);
    }
  }
  __syncthreads();

  f32x4 acc1[4], accS[4];
  #pragma unroll
  for (int jm=0;jm<4;jm++){ acc1[jm]=(f32x4)0.f; accS[jm]=(f32x4)0.f; }

  // conv1 (512->256) + shortcut (512->256)
  #pragma unroll
  for (int ks=0;ks<16;ks++){
    const int kcol = ks*32 + quad*8;
    short8 xb = *reinterpret_cast<const short8*>(&Xb[l15*520 + kcol]);
    #pragma unroll
    for (int jm=0;jm<4;jm++){
      int row = (w*4+jm)*16 + l15;
      short8 a1 = *reinterpret_cast<const short8*>(wv1b + row*512 + kcol);
      short8 as = *reinterpret_cast<const short8*>(wvsb + row*512 + kcol);
      acc1[jm] = __builtin_amdgcn_mfma_f32_16x16x32_bf16(a1, xb, acc1[jm], 0,0,0);
      accS[jm] = __builtin_amdgcn_mfma_f32_16x16x32_bf16(as, xb, accS[jm], 0,0,0);
    }
  }
  // epilogue: relu(conv1+bias) -> hidB
  #pragma unroll
  for (int jm=0;jm<4;jm++){
    #pragma unroll
    for (int r=0;r<4;r++){
      int h = (w*4+jm)*16 + quad*4 + r;
      hidB[l15*264 + h] = (short)f2b(fmaxf(acc1[jm][r] + bv1[h], 0.f));
    }
  }
  __syncthreads();

  // wv2 (256->256) accumulating into shortcut acc
  #pragma unroll
  for (int ks=0;ks<8;ks++){
    const int kcol = ks*32 + quad*8;
    short8 hb = *reinterpret_cast<const short8*>(&hidB[l15*264 + kcol]);
    #pragma unroll
    for (int jm=0;jm<4;jm++){
      int row = (w*4+jm)*16 + l15;
      short8 a = *reinterpret_cast<const short8*>(wv2b + row*256 + kcol);
      accS[jm] = __builtin_amdgcn_mfma_f32_16x16x32_bf16(a, hb, accS[jm], 0,0,0);
    }
  }
  // epilogue: value -> valF (fp32) + valB (bf16)
  #pragma unroll
  for (int jm=0;jm<4;jm++){
    #pragma unroll
    for (int r=0;r<4;r++){
      int c = (w*4+jm)*16 + quad*4 + r;
      float v = accS[jm][r] + bv2[c] + bvs[c];
      valF[l15*264 + c] = v;
      valB[l15*264 + c] = (short)f2b(v);
    }
  }
  __syncthreads();

  // coalesced valueT store; thread t = channel
  #pragma unroll
  for (int p=0;p<PTS;p++)
    valueT[((size_t)(b*Nq + n0 + p))*Cq + t] = valF[p*264 + t];

  // projections: wave w handles m-tile w for each of k/q/v
  {
    f32x4 pk4=(f32x4)0.f, pq4=(f32x4)0.f, pv4=(f32x4)0.f;
    #pragma unroll
    for (int ks=0;ks<8;ks++){
      const int kcol = ks*32 + quad*8;
      short8 xk = *reinterpret_cast<const short8*>(&Xb[l15*520 + kcol]);
      short8 xq = *reinterpret_cast<const short8*>(&Xb[l15*520 + 256 + kcol]);
      short8 xv = *reinterpret_cast<const short8*>(&valB[l15*264 + kcol]);
      int row = w*16 + l15;
      short8 ak = *reinterpret_cast<const short8*>(wkb  + row*256 + kcol);
      short8 aq = *reinterpret_cast<const short8*>(wqb  + row*256 + kcol);
      short8 av = *reinterpret_cast<const short8*>(wvalb+ row*256 + kcol);
      pk4 = __builtin_amdgcn_mfma_f32_16x16x32_bf16(ak, xk, pk4, 0,0,0);
      pq4 = __builtin_amdgcn_mfma_f32_16x16x32_bf16(aq, xq, pq4, 0,0,0);
      pv4 = __builtin_amdgcn_mfma_f32_16x16x32_bf16(av, xv, pv4, 0,0,0);
    }
    #pragma unroll
    for (int r=0;r<4;r++){
      int o = w*16 + quad*4 + r;
      int n = n0 + l15;
      size_t base = ((size_t)(b*Nq+n))*Dq + o;
      kfT[base] = (short)f2b(pk4[r] + bk[o]);
      qfT[base] = (short)f2b(pq4[r] + bq[o]);
      vfT[base] = (short)f2b(pv4[r] + bval[o]);
    }
  }
}

// ---------------------------------------------------------------------------
// Kernel 2: KNN — wave-per-point, distances in registers (unchanged).
// ---------------------------------------------------------------------------
__global__ __launch_bounds__(256) void k_knn(const float* __restrict__ pos,
                                             int* __restrict__ idxT)
{
  const int t = threadIdx.x;
  const int lane = t & 63;
  const int w = t >> 6;
  const int pid = blockIdx.x*4 + w;
  const int b = pid >> 11;
  const int n = pid & (Nq-1);
  const float* px = pos + (size_t)(b*3+0)*Nq;
  const float* py = pos + (size_t)(b*3+1)*Nq;
  const float* pz = pos + (size_t)(b*3+2)*Nq;
  const float xn=px[n], yn=py[n], zn=pz[n];
  const float sqn = __fadd_rn(__fadd_rn(__fmul_rn(xn,xn),__fmul_rn(yn,yn)),__fmul_rn(zn,zn));

  float d[32];
  #pragma unroll
  for (int i=0;i<32;i++){
    int j = i*64 + lane;
    float x=px[j], y=py[j], z=pz[j];
    float sqj = __fadd_rn(__fadd_rn(__fmul_rn(x,x),__fmul_rn(y,y)),__fmul_rn(z,z));
    float dot = __fadd_rn(__fadd_rn(__fmul_rn(xn,x),__fmul_rn(yn,y)),__fmul_rn(zn,z));
    d[i] = __fsub_rn(__fadd_rn(sqn,sqj), __fmul_rn(2.0f,dot));
  }

  float last_d = -3.4e38f; int last_j = -1;
  for (int s=0;s<KNNq;s++){
    float best = 3.4e38f; int bj = 1<<30;
    #pragma unroll
    for (int i=0;i<32;i++){
      int j = i*64 + lane;
      float dv = d[i];
      bool valid = (dv > last_d) || (dv == last_d && j > last_j);
      if (valid && dv < best){ best = dv; bj = j; }
    }
    #pragma unroll
    for (int off=1; off<64; off<<=1){
      float ob = __shfl_xor(best, off);
      int   oj = __shfl_xor(bj,  off);
      if (ob < best || (ob == best && oj < bj)){ best = ob; bj = oj; }
    }
    if (lane == 0) idxT[(size_t)pid*KNNq + s] = bj;
    last_d = best; last_j = bj;
  }
}

// ---------------------------------------------------------------------------
// Kernel 3: fused attn (unchanged from round 4 — MFMA GEMMs + in-register
// softmax; coalesced weight reads).
// ---------------------------------------------------------------------------
__global__ __launch_bounds__(256) void k_attn(
  const float* __restrict__ pos,
  const float* __restrict__ valueT, const short* __restrict__ kfT,
  const short* __restrict__ qfT,    const short* __restrict__ vfT,
  const int* __restrict__ idxT,
  const float* __restrict__ pw1, const float* __restrict__ pb1,
  const float* __restrict__ pg,  const float* __restrict__ pbt,
  const float* __restrict__ prm, const float* __restrict__ prv,
  const float* __restrict__ pw2T, const float* __restrict__ pb2,
  const short* __restrict__ aw1b, const float* __restrict__ ab1,
  const float* __restrict__ ag,  const float* __restrict__ abt,
  const float* __restrict__ arm, const float* __restrict__ arv,
  const short* __restrict__ ctwT,
  const float* __restrict__ weT,  const float* __restrict__ be,
  float* __restrict__ out)
{
  __shared__ __align__(16) float hS[PHq*KNNq];
  __shared__ __align__(16) float vg[Dq*KNNq];
  __shared__ __align__(16) short uT[32*72];
  __shared__ __align__(16) short sT[32*264];
  __shared__ __align__(16) float aggS[DMq];
  __shared__ float scS[DMq], sh2S[DMq];
  __shared__ float prl[3*KNNq];
  __shared__ int   nb[KNNq];

  const int t = threadIdx.x;
  const int b = blockIdx.x >> 11;
  const int n = blockIdx.x & (Nq-1);
  const int lane = t & 63, quad = lane >> 4, l15 = lane & 15, w = t >> 6;

  if (t < KNNq){
    int j = idxT[((size_t)(b*Nq+n))*KNNq + t];
    nb[t] = j;
    #pragma unroll
    for (int d=0; d<3; d++){
      prl[d*KNNq+t] = pos[((size_t)(b*3+d))*Nq + n] - pos[((size_t)(b*3+d))*Nq + j];
    }
  }
  {
    float sc = ag[t] * rsqrtf(arv[t] + 1e-5f);
    scS[t]  = sc;
    sh2S[t] = ab1[t]*sc + (abt[t] - arm[t]*sc);
  }
  for (int i = 720 + t; i < 1152; i += 256) ((unsigned*)uT)[i] = 0u;
  __syncthreads();

  // ---- stage 1: pos_mlp hidden ----
  {
    const int ph = t & 63, kq = t >> 6;
    float sc = pg[ph] * rsqrtf(prv[ph] + 1e-5f);
    float sh = pbt[ph] - prm[ph] * sc;
    float w0 = pw1[ph*3+0], w1 = pw1[ph*3+1], w2 = pw1[ph*3+2];
    float bb = pb1[ph];
    #pragma unroll
    for (int m=0;m<5;m++){
      int k = kq + (m<<2);
      float h = w0*prl[k] + w1*prl[KNNq+k] + w2*prl[2*KNNq+k] + bb;
      hS[ph*KNNq+k] = fmaxf(h*sc + sh, 0.f);
    }
  }
  __syncthreads();

  // ---- stage 2: pos_emb + build uT (bf16) and vg (fp32) ----
  {
    const int o = t & 63, kq = t >> 6;
    float qv = b2f(qfT[((size_t)(b*Nq+n))*Dq + o]);
    float pb = pb2[o];
    float acc[5];
    #pragma unroll
    for (int m=0;m<5;m++) acc[m]=pb;
    for (int ph=0; ph<PHq; ph++){
      float wv = pw2T[ph*64 + o];
      #pragma unroll
      for (int m=0;m<5;m++) acc[m] = fmaf(wv, hS[ph*KNNq + kq + (m<<2)], acc[m]);
    }
    #pragma unroll
    for (int m=0;m<5;m++){
      int k = kq + (m<<2);
      int j = nb[k];
      float kg = b2f(kfT[((size_t)(b*Nq+j))*Dq + o]);
      float vv = b2f(vfT[((size_t)(b*Nq+j))*Dq + o]);
      uT[k*72 + o]  = (short)f2b((qv - kg) + acc[m]);
      vg[o*KNNq+k]  = vv + acc[m];
    }
  }
  __syncthreads();

  // ---- stage 3: conv1 (64->256) via MFMA; epilogue bn+relu -> sT ----
  {
    f32x4 accC[4][2];
    #pragma unroll
    for (int jm=0;jm<4;jm++){ accC[jm][0]=(f32x4)0.f; accC[jm][1]=(f32x4)0.f; }
    #pragma unroll
    for (int ks=0;ks<2;ks++){
      const int kcol = ks*32 + quad*8;
      short8 b0 = *reinterpret_cast<const short8*>(&uT[ l15     *72 + kcol]);
      short8 b1 = *reinterpret_cast<const short8*>(&uT[(16+l15)*72 + kcol]);
      #pragma unroll
      for (int jm=0;jm<4;jm++){
        int mt = w*4 + jm;
        short8 a = *reinterpret_cast<const short8*>(aw1b + ((mt*16+l15)*64 + kcol));
        accC[jm][0] = __builtin_amdgcn_mfma_f32_16x16x32_bf16(a, b0, accC[jm][0], 0,0,0);
        accC[jm][1] = __builtin_amdgcn_mfma_f32_16x16x32_bf16(a, b1, accC[jm][1], 0,0,0);
      }
    }
    #pragma unroll
    for (int jm=0;jm<4;jm++){
      int mt = w*4 + jm;
      int cb = mt*16 + quad*4;
      #pragma unroll
      for (int nt=0;nt<2;nt++){
        int k = nt*16 + l15;
        short4v pk;
        #pragma unroll
        for (int r=0;r<4;r++){
          int c = cb + r;
          float s = fmaxf(accC[jm][nt][r]*scS[c] + sh2S[c], 0.f);
          pk[r] = (short)f2b(s);
        }
        *reinterpret_cast<short4v*>(&sT[k*264 + cb]) = pk;
      }
    }
  }
  __syncthreads();

  // ---- stage 4: convT (256->256) via MFMA + softmax + aggregate ----
  {
    f32x4 accT[4][2];
    #pragma unroll
    for (int jm=0;jm<4;jm++){ accT[jm][0]=(f32x4)0.f; accT[jm][1]=(f32x4)0.f; }
    #pragma unroll
    for (int ks=0;ks<8;ks++){
      const int kcol = ks*32 + quad*8;
      short8 b0 = *reinterpret_cast<const short8*>(&sT[ l15     *264 + kcol]);
      short8 b1 = *reinterpret_cast<const short8*>(&sT[(16+l15)*264 + kcol]);
      #pragma unroll
      for (int jm=0;jm<4;jm++){
        int mt = w*4 + jm;
        short8 a = *reinterpret_cast<const short8*>(ctwT + ((size_t)(mt*16+l15)*256 + kcol));
        accT[jm][0] = __builtin_amdgcn_mfma_f32_16x16x32_bf16(a, b0, accT[jm][0], 0,0,0);
        accT[jm][1] = __builtin_amdgcn_mfma_f32_16x16x32_bf16(a, b1, accT[jm][1], 0,0,0);
      }
    }
    const bool in1 = (l15 < 4);
    #pragma unroll
    for (int jm=0;jm<4;jm++){
      int mt = w*4 + jm;
      #pragma unroll
      for (int r=0;r<4;r++){
        int row = mt*16 + quad*4 + r;
        int o = row >> 2;
        float v0 = accT[jm][0][r];
        float v1 = accT[jm][1][r];
        float m = qmax4(fmaxf(v0, in1 ? v1 : v0));
        float e0 = __expf(v0 - m);
        float e1 = in1 ? __expf(v1 - m) : 0.f;
        float ssum = qsum4(e0 + e1);
        float vg0 = vg[o*KNNq + l15];
        int i1 = in1 ? (o*KNNq + 16 + l15) : 0;
        float p = e0*vg0 + (in1 ? e1*vg[i1] : 0.f);
        float acc = qsum4(p);
        if (l15 == 0) aggS[row] = acc / ssum;
      }
    }
  }
  __syncthreads();

  // ---- stage 5: conv_end (64->256) + bias + identity ----
  {
    float y[4] = {0,0,0,0};
    for (int o2=0;o2<Dq;o2++){
      float wv = weT[o2*256 + t];
      float a4[4];
      ld16(a4, &aggS[o2*4]);
      #pragma unroll
      for (int j=0;j<4;j++) y[j]=fmaf(wv,a4[j],y[j]);
    }
    float bias = be[t] + valueT[((size_t)(b*Nq+n))*Cq + t];
    float4 o4;
    o4.x = y[0]+bias; o4.y = y[1]+bias; o4.z = y[2]+bias; o4.w = y[3]+bias;
    size_t ob = ((size_t)(b*Cq + t))*((size_t)Nq*UPq) + (size_t)n*UPq;
    *reinterpret_cast<float4*>(out + ob) = o4;
  }
}

// ---------------------------------------------------------------------------
extern "C" void kernel_launch(void* const* d_in, const int* in_sizes, int n_in,
                              void* d_out, int out_size, void* d_ws, size_t ws_size,
                              hipStream_t stream)
{
  const float* pos  = (const float*)d_in[0];
  const float* key  = (const float*)d_in[1];
  const float* qry  = (const float*)d_in[2];
  const float* wv1  = (const float*)d_in[3];
  const float* bv1  = (const float*)d_in[4];
  const float* wv2  = (const float*)d_in[5];
  const float* bv2  = (const float*)d_in[6];
  const float* wvs  = (const float*)d_in[7];
  const float* bvs  = (const float*)d_in[8];
  const float* wk   = (const float*)d_in[9];
  const float* bk   = (const float*)d_in[10];
  const float* wq   = (const float*)d_in[11];
  const float* bq   = (const float*)d_in[12];
  const float* wval = (const float*)d_in[13];
  const float* bval = (const float*)d_in[14];
  const float* pw1  = (const float*)d_in[15];
  const float* pb1  = (const float*)d_in[16];
  const float* pg   = (const float*)d_in[17];
  const float* pbt  = (const float*)d_in[18];
  const float* prm  = (const float*)d_in[19];
  const float* prv  = (const float*)d_in[20];
  const float* pw2  = (const float*)d_in[21];
  const float* pb2  = (const float*)d_in[22];
  const float* aw1  = (const float*)d_in[23];
  const float* ab1  = (const float*)d_in[24];
  const float* ag   = (const float*)d_in[25];
  const float* abt  = (const float*)d_in[26];
  const float* arm  = (const float*)d_in[27];
  const float* arv  = (const float*)d_in[28];
  const float* ctw  = (const float*)d_in[29];
  const float* we   = (const float*)d_in[31];
  const float* be   = (const float*)d_in[32];

  char* ws = (char*)d_ws;
  float* valueT = (float*)(ws);                    // 8 MB fp32
  short* kfT    = (short*)(ws + 8388608);          // 1 MB bf16
  short* qfT    = (short*)(ws + 9437184);
  short* vfT    = (short*)(ws + 10485760);
  int*   idxT   = (int*)  (ws + 11534336);         // 640 KB
  short* aw1b   = (short*)(ws + 12189696);         // 32 KB
  short* ctwT   = (short*)(ws + 12222464);         // 128 KB
  short* wv1b   = (short*)(ws + 12353536);         // 256 KB
  short* wvsb   = (short*)(ws + 12615680);         // 256 KB
  short* wv2b   = (short*)(ws + 12877824);         // 128 KB
  short* wkb    = (short*)(ws + 13008896);         // 32 KB
  short* wqb    = (short*)(ws + 13041664);         // 32 KB
  short* wvalb  = (short*)(ws + 13074432);         // 32 KB
  float* pw2T   = (float*)(ws + 13107200);         // 16 KB
  float* weT    = (float*)(ws + 13123584);         // 64 KB
  float* out    = (float*)d_out;

  k_prep<<<dim3(1872), dim3(256), 0, stream>>>(
      aw1, ctw, wv1, wvs, wv2, wk, wq, wval, pw2, we,
      aw1b, ctwT, wv1b, wvsb, wv2b, wkb, wqb, wvalb, pw2T, weT);
  k_value<<<dim3(Bq*Nq/PTS), dim3(256), 0, stream>>>(
      key, qry, wv1b, wvsb, wv2b, wkb, wqb, wvalb,
      bv1, bv2, bvs, bk, bq, bval,
      valueT, kfT, qfT, vfT);
  k_knn<<<dim3(Bq*Nq/4), dim3(256), 0, stream>>>(pos, idxT);
  k_attn<<<dim3(Bq*Nq), dim3(256), 0, stream>>>(
      pos, valueT, kfT, qfT, vfT, idxT,
      pw1, pb1, pg, pbt, prm, prv, pw2T, pb2,
      aw1b, ab1, ag, abt, arm, arv, ctwT, weT, be, out);
}

// Round 6
// 457.321 us; speedup vs baseline: 2.3226x; 1.2814x over previous
//
#include <hip/hip_runtime.h>
#include <hip/hip_bf16.h>

#define Bq 4
#define Nq 2048
#define Cq 256
#define Dq 64
#define UPq 4
#define KNNq 20
#define PHq 64
#define DMq 256   // D*MULT
#define PTS 16    // points per block in k_value

typedef __attribute__((ext_vector_type(8))) short short8;
typedef __attribute__((ext_vector_type(4))) short short4v;
typedef __attribute__((ext_vector_type(4))) float f32x4;
typedef __hip_bfloat16 bf16;

__device__ __forceinline__ void ld16(float* d, const float* s){
  *reinterpret_cast<float4*>(d) = *reinterpret_cast<const float4*>(s);
}
__device__ __forceinline__ unsigned short f2b(float x){
  bf16 h = __float2bfloat16(x);
  return *reinterpret_cast<unsigned short*>(&h);
}
__device__ __forceinline__ float b2f(short s){
  return __bfloat162float(*reinterpret_cast<bf16*>(&s));
}

// ---------------------------------------------------------------------------
// Kernel 0: weight prep — all bf16, row-major (straight converts) except the
// one genuine transpose ctwT.
// ---------------------------------------------------------------------------
__global__ __launch_bounds__(256) void k_prep(
    const float* __restrict__ aw1, const float* __restrict__ ctw,
    const float* __restrict__ wv1, const float* __restrict__ wvs,
    const float* __restrict__ wv2, const float* __restrict__ wk,
    const float* __restrict__ wq,  const float* __restrict__ wval,
    const float* __restrict__ pw2, const float* __restrict__ we,
    short* __restrict__ aw1b, short* __restrict__ ctwT,
    short* __restrict__ wv1b, short* __restrict__ wvsb,
    short* __restrict__ wv2b, short* __restrict__ wkb,
    short* __restrict__ wqb,  short* __restrict__ wvalb,
    short* __restrict__ pw2b, short* __restrict__ web)
{
  const int t = threadIdx.x, bidx = blockIdx.x;
  if (bidx < 64){                                  // aw1b 256x64 bf16
    int i = bidx*256 + t;
    aw1b[i] = (short)f2b(aw1[i]);
  } else if (bidx < 320){                          // ctwT[t][c] = ctw[c][t]
    int c = bidx - 64;
    ctwT[t*256 + c] = (short)f2b(ctw[c*256 + t]);
  } else if (bidx < 832){                          // wv1b straight 256x512
    int i = (bidx-320)*256 + t;
    wv1b[i] = (short)f2b(wv1[i]);
  } else if (bidx < 1344){                         // wvsb straight
    int i = (bidx-832)*256 + t;
    wvsb[i] = (short)f2b(wvs[i]);
  } else if (bidx < 1600){                         // wv2b straight 256x256
    int i = (bidx-1344)*256 + t;
    wv2b[i] = (short)f2b(wv2[i]);
  } else if (bidx < 1664){                         // wkb straight 64x256
    int i = (bidx-1600)*256 + t;
    wkb[i] = (short)f2b(wk[i]);
  } else if (bidx < 1728){
    int i = (bidx-1664)*256 + t;
    wqb[i] = (short)f2b(wq[i]);
  } else if (bidx < 1792){
    int i = (bidx-1728)*256 + t;
    wvalb[i] = (short)f2b(wval[i]);
  } else if (bidx < 1808){                         // pw2b straight 64x64
    int i = (bidx-1792)*256 + t;
    pw2b[i] = (short)f2b(pw2[i]);
  } else {                                         // web straight 256x64
    int i = (bidx-1808)*256 + t;
    web[i] = (short)f2b(we[i]);
  }
}

// ---------------------------------------------------------------------------
// Kernel 1: value MLP + projections, fully MFMA (unchanged from round 5).
// ---------------------------------------------------------------------------
__global__ __launch_bounds__(256) void k_value(
    const float* __restrict__ key, const float* __restrict__ query,
    const short* __restrict__ wv1b, const short* __restrict__ wvsb,
    const short* __restrict__ wv2b, const short* __restrict__ wkb,
    const short* __restrict__ wqb,  const short* __restrict__ wvalb,
    const float* __restrict__ bv1, const float* __restrict__ bv2,
    const float* __restrict__ bvs, const float* __restrict__ bk,
    const float* __restrict__ bq,  const float* __restrict__ bval,
    float* __restrict__ valueT, short* __restrict__ kfT,
    short* __restrict__ qfT,    short* __restrict__ vfT)
{
  __shared__ __align__(16) short Xb[16*520];
  __shared__ __align__(16) short hidB[16*264];
  __shared__ __align__(16) short valB[16*264];
  __shared__ __align__(16) float valF[16*264];
  const int t = threadIdx.x;
  const int b = blockIdx.x >> 7;
  const int n0 = (blockIdx.x & 127) * PTS;
  const int lane = t & 63, quad = lane >> 4, l15 = lane & 15, w = t >> 6;

  {
    const float* kp = key   + ((size_t)(b*Cq + t))*Nq + n0;
    const float* qp = query + ((size_t)(b*Cq + t))*Nq + n0;
    float kv[16], qv[16];
    #pragma unroll
    for (int p=0;p<PTS;p+=4){ ld16(&kv[p], kp+p); ld16(&qv[p], qp+p); }
    #pragma unroll
    for (int p=0;p<PTS;p++){
      Xb[p*520 + t]       = (short)f2b(kv[p]);
      Xb[p*520 + 256 + t] = (short)f2b(qv[p]);
    }
  }
  __syncthreads();

  f32x4 acc1[4], accS[4];
  #pragma unroll
  for (int jm=0;jm<4;jm++){ acc1[jm]=(f32x4)0.f; accS[jm]=(f32x4)0.f; }

  #pragma unroll
  for (int ks=0;ks<16;ks++){
    const int kcol = ks*32 + quad*8;
    short8 xb = *reinterpret_cast<const short8*>(&Xb[l15*520 + kcol]);
    #pragma unroll
    for (int jm=0;jm<4;jm++){
      int row = (w*4+jm)*16 + l15;
      short8 a1 = *reinterpret_cast<const short8*>(wv1b + row*512 + kcol);
      short8 as = *reinterpret_cast<const short8*>(wvsb + row*512 + kcol);
      acc1[jm] = __builtin_amdgcn_mfma_f32_16x16x32_bf16(a1, xb, acc1[jm], 0,0,0);
      accS[jm] = __builtin_amdgcn_mfma_f32_16x16x32_bf16(as, xb, accS[jm], 0,0,0);
    }
  }
  #pragma unroll
  for (int jm=0;jm<4;jm++){
    #pragma unroll
    for (int r=0;r<4;r++){
      int h = (w*4+jm)*16 + quad*4 + r;
      hidB[l15*264 + h] = (short)f2b(fmaxf(acc1[jm][r] + bv1[h], 0.f));
    }
  }
  __syncthreads();

  #pragma unroll
  for (int ks=0;ks<8;ks++){
    const int kcol = ks*32 + quad*8;
    short8 hb = *reinterpret_cast<const short8*>(&hidB[l15*264 + kcol]);
    #pragma unroll
    for (int jm=0;jm<4;jm++){
      int row = (w*4+jm)*16 + l15;
      short8 a = *reinterpret_cast<const short8*>(wv2b + row*256 + kcol);
      accS[jm] = __builtin_amdgcn_mfma_f32_16x16x32_bf16(a, hb, accS[jm], 0,0,0);
    }
  }
  #pragma unroll
  for (int jm=0;jm<4;jm++){
    #pragma unroll
    for (int r=0;r<4;r++){
      int c = (w*4+jm)*16 + quad*4 + r;
      float v = accS[jm][r] + bv2[c] + bvs[c];
      valF[l15*264 + c] = v;
      valB[l15*264 + c] = (short)f2b(v);
    }
  }
  __syncthreads();

  #pragma unroll
  for (int p=0;p<PTS;p++)
    valueT[((size_t)(b*Nq + n0 + p))*Cq + t] = valF[p*264 + t];

  {
    f32x4 pk4=(f32x4)0.f, pq4=(f32x4)0.f, pv4=(f32x4)0.f;
    #pragma unroll
    for (int ks=0;ks<8;ks++){
      const int kcol = ks*32 + quad*8;
      short8 xk = *reinterpret_cast<const short8*>(&Xb[l15*520 + kcol]);
      short8 xq = *reinterpret_cast<const short8*>(&Xb[l15*520 + 256 + kcol]);
      short8 xv = *reinterpret_cast<const short8*>(&valB[l15*264 + kcol]);
      int row = w*16 + l15;
      short8 ak = *reinterpret_cast<const short8*>(wkb  + row*256 + kcol);
      short8 aq = *reinterpret_cast<const short8*>(wqb  + row*256 + kcol);
      short8 av = *reinterpret_cast<const short8*>(wvalb+ row*256 + kcol);
      pk4 = __builtin_amdgcn_mfma_f32_16x16x32_bf16(ak, xk, pk4, 0,0,0);
      pq4 = __builtin_amdgcn_mfma_f32_16x16x32_bf16(aq, xq, pq4, 0,0,0);
      pv4 = __builtin_amdgcn_mfma_f32_16x16x32_bf16(av, xv, pv4, 0,0,0);
    }
    #pragma unroll
    for (int r=0;r<4;r++){
      int o = w*16 + quad*4 + r;
      int n = n0 + l15;
      size_t base = ((size_t)(b*Nq+n))*Dq + o;
      kfT[base] = (short)f2b(pk4[r] + bk[o]);
      qfT[base] = (short)f2b(pq4[r] + bq[o]);
      vfT[base] = (short)f2b(pv4[r] + bval[o]);
    }
  }
}

// ---------------------------------------------------------------------------
// Kernel 2: KNN — wave-per-point, distances in registers (unchanged).
// ---------------------------------------------------------------------------
__global__ __launch_bounds__(256) void k_knn(const float* __restrict__ pos,
                                             int* __restrict__ idxT)
{
  const int t = threadIdx.x;
  const int lane = t & 63;
  const int w = t >> 6;
  const int pid = blockIdx.x*4 + w;
  const int b = pid >> 11;
  const int n = pid & (Nq-1);
  const float* px = pos + (size_t)(b*3+0)*Nq;
  const float* py = pos + (size_t)(b*3+1)*Nq;
  const float* pz = pos + (size_t)(b*3+2)*Nq;
  const float xn=px[n], yn=py[n], zn=pz[n];
  const float sqn = __fadd_rn(__fadd_rn(__fmul_rn(xn,xn),__fmul_rn(yn,yn)),__fmul_rn(zn,zn));

  float d[32];
  #pragma unroll
  for (int i=0;i<32;i++){
    int j = i*64 + lane;
    float x=px[j], y=py[j], z=pz[j];
    float sqj = __fadd_rn(__fadd_rn(__fmul_rn(x,x),__fmul_rn(y,y)),__fmul_rn(z,z));
    float dot = __fadd_rn(__fadd_rn(__fmul_rn(xn,x),__fmul_rn(yn,y)),__fmul_rn(zn,z));
    d[i] = __fsub_rn(__fadd_rn(sqn,sqj), __fmul_rn(2.0f,dot));
  }

  float last_d = -3.4e38f; int last_j = -1;
  for (int s=0;s<KNNq;s++){
    float best = 3.4e38f; int bj = 1<<30;
    #pragma unroll
    for (int i=0;i<32;i++){
      int j = i*64 + lane;
      float dv = d[i];
      bool valid = (dv > last_d) || (dv == last_d && j > last_j);
      if (valid && dv < best){ best = dv; bj = j; }
    }
    #pragma unroll
    for (int off=1; off<64; off<<=1){
      float ob = __shfl_xor(best, off);
      int   oj = __shfl_xor(bj,  off);
      if (ob < best || (ob == best && oj < bj)){ best = ob; bj = oj; }
    }
    if (lane == 0) idxT[(size_t)pid*KNNq + s] = bj;
    last_d = best; last_j = bj;
  }
}

// ---------------------------------------------------------------------------
// Kernel 3: fused attn, P=2 points per block. All five matmuls are bf16 MFMA.
// Column layout: pk = p*24 + k (k<20 valid, pad finite). Softmax via LDS
// transpose pass (no shuffle storm). 6 barriers per block = 3 per point.
// ---------------------------------------------------------------------------
__global__ __launch_bounds__(256) void k_attn(
  const float* __restrict__ pos,
  const float* __restrict__ valueT, const short* __restrict__ kfT,
  const short* __restrict__ qfT,    const short* __restrict__ vfT,
  const int* __restrict__ idxT,
  const float* __restrict__ pw1, const float* __restrict__ pb1,
  const float* __restrict__ pg,  const float* __restrict__ pbt,
  const float* __restrict__ prm, const float* __restrict__ prv,
  const short* __restrict__ pw2b, const float* __restrict__ pb2,
  const short* __restrict__ aw1b, const float* __restrict__ ab1,
  const float* __restrict__ ag,  const float* __restrict__ abt,
  const float* __restrict__ arm, const float* __restrict__ arv,
  const short* __restrict__ ctwT,
  const short* __restrict__ web,  const float* __restrict__ be,
  float* __restrict__ out)
{
  __shared__ __align__(16) short uT[48*72];        // [pk][o]   B-layout, 6912 B
  __shared__ __align__(16) short sT[48*264];       // [pk][c]   B-layout, 25344 B
  __shared__ __align__(16) char  slotA[26624];     // hB[48][72] then ctS[256][52]
  __shared__ __align__(16) short vgB[64*56];       // [o][pk]   7168 B
  __shared__ __align__(16) short aggB[16*72];      // [(p,r)][o] B-layout, 2304 B
  __shared__ float scS[DMq], sh2S[DMq];
  __shared__ float prl[3*48];
  __shared__ int   nb[48];

  short* hB  = (short*)slotA;
  short* ctS = (short*)slotA;

  const int t = threadIdx.x;
  const int b  = blockIdx.x >> 10;
  const int n0 = (blockIdx.x & 1023) * 2;
  const int lane = t & 63, quad = lane >> 4, l15 = lane & 15, w = t >> 6;
  const size_t bN = (size_t)b * Nq;

  // ---- stage 0: gather neighbors, bn coeffs, zero aggB pad rows ----
  if (t < 48){
    int p = (t >= 24);
    int k = t - p*24;
    int nn = n0 + p;
    int j = (k < KNNq) ? idxT[(bN + nn)*KNNq + k] : nn;   // pad -> self (prl=0)
    nb[t] = j;
    #pragma unroll
    for (int d=0; d<3; d++){
      prl[d*48+t] = pos[((size_t)(b*3+d))*Nq + nn] - pos[((size_t)(b*3+d))*Nq + j];
    }
  }
  {
    float sc = ag[t] * rsqrtf(arv[t] + 1e-5f);
    scS[t]  = sc;
    sh2S[t] = ab1[t]*sc + (abt[t] - arm[t]*sc);
  }
  for (int i = t; i < 576; i += 256) aggB[576 + i] = 0;   // rows 8..15
  __syncthreads();

  // ---- stage 1: pos_mlp hidden -> hB (bf16 B-layout [pk][ph]) ----
  {
    const int ph = t & 63, pkq = t >> 6;
    float sc = pg[ph] * rsqrtf(prv[ph] + 1e-5f);
    float sh = pbt[ph] - prm[ph] * sc;
    float w0 = pw1[ph*3+0], w1 = pw1[ph*3+1], w2 = pw1[ph*3+2];
    float bb = pb1[ph];
    #pragma unroll
    for (int m=0;m<12;m++){
      int pk = pkq + m*4;
      float h = w0*prl[pk] + w1*prl[48+pk] + w2*prl[96+pk] + bb;
      hB[pk*72 + ph] = (short)f2b(fmaxf(h*sc + sh, 0.f));
    }
  }
  __syncthreads();

  // ---- stage 2: pos_emb via MFMA (M=64,K=64,N=48); epilogue builds uT, vgB ----
  {
    f32x4 accP[3];
    #pragma unroll
    for (int nt=0;nt<3;nt++) accP[nt]=(f32x4)0.f;
    #pragma unroll
    for (int ks=0;ks<2;ks++){
      const int kcol = ks*32 + quad*8;
      short8 a = *reinterpret_cast<const short8*>(pw2b + (w*16+l15)*64 + kcol);
      #pragma unroll
      for (int nt=0;nt<3;nt++){
        short8 bb = *reinterpret_cast<const short8*>(&hB[(nt*16+l15)*72 + kcol]);
        accP[nt] = __builtin_amdgcn_mfma_f32_16x16x32_bf16(a, bb, accP[nt], 0,0,0);
      }
    }
    #pragma unroll
    for (int nt=0;nt<3;nt++){
      int pk = nt*16 + l15;
      int p = (pk >= 24);
      int j = nb[pk];
      int nn = n0 + p;
      #pragma unroll
      for (int r=0;r<4;r++){
        int o = w*16 + quad*4 + r;
        float pe = accP[nt][r] + pb2[o];
        float qv = b2f(qfT[(bN+nn)*Dq + o]);
        float kg = b2f(kfT[(bN+j)*Dq + o]);
        float vv = b2f(vfT[(bN+j)*Dq + o]);
        uT[pk*72 + o]  = (short)f2b((qv - kg) + pe);
        vgB[o*56 + pk] = (short)f2b(vv + pe);
      }
    }
  }
  __syncthreads();

  // ---- stage 3: attn conv1 (64->256) MFMA; bn+relu -> sT ----
  {
    f32x4 accC[4][3];
    #pragma unroll
    for (int jm=0;jm<4;jm++)
      #pragma unroll
      for (int nt=0;nt<3;nt++) accC[jm][nt]=(f32x4)0.f;
    #pragma unroll
    for (int ks=0;ks<2;ks++){
      const int kcol = ks*32 + quad*8;
      short8 bb[3];
      #pragma unroll
      for (int nt=0;nt<3;nt++)
        bb[nt] = *reinterpret_cast<const short8*>(&uT[(nt*16+l15)*72 + kcol]);
      #pragma unroll
      for (int jm=0;jm<4;jm++){
        int mt = w*4 + jm;
        short8 a = *reinterpret_cast<const short8*>(aw1b + (mt*16+l15)*64 + kcol);
        #pragma unroll
        for (int nt=0;nt<3;nt++)
          accC[jm][nt] = __builtin_amdgcn_mfma_f32_16x16x32_bf16(a, bb[nt], accC[jm][nt], 0,0,0);
      }
    }
    #pragma unroll
    for (int jm=0;jm<4;jm++){
      int cb = (w*4+jm)*16 + quad*4;
      #pragma unroll
      for (int nt=0;nt<3;nt++){
        int pk = nt*16 + l15;
        short4v pkv;
        #pragma unroll
        for (int r=0;r<4;r++){
          int c = cb + r;
          pkv[r] = (short)f2b(fmaxf(accC[jm][nt][r]*scS[c] + sh2S[c], 0.f));
        }
        *reinterpret_cast<short4v*>(&sT[pk*264 + cb]) = pkv;
      }
    }
  }
  __syncthreads();

  // ---- stage 4: convT (256->256) MFMA; write ct to ctS (bf16) ----
  {
    f32x4 accT[4][3];
    #pragma unroll
    for (int jm=0;jm<4;jm++)
      #pragma unroll
      for (int nt=0;nt<3;nt++) accT[jm][nt]=(f32x4)0.f;
    #pragma unroll
    for (int ks=0;ks<8;ks++){
      const int kcol = ks*32 + quad*8;
      short8 bb[3];
      #pragma unroll
      for (int nt=0;nt<3;nt++)
        bb[nt] = *reinterpret_cast<const short8*>(&sT[(nt*16+l15)*264 + kcol]);
      #pragma unroll
      for (int jm=0;jm<4;jm++){
        int mt = w*4 + jm;
        short8 a = *reinterpret_cast<const short8*>(ctwT + (size_t)(mt*16+l15)*256 + kcol);
        #pragma unroll
        for (int nt=0;nt<3;nt++)
          accT[jm][nt] = __builtin_amdgcn_mfma_f32_16x16x32_bf16(a, bb[nt], accT[jm][nt], 0,0,0);
      }
    }
    __syncthreads();   // hB (slotA) fully dead; now reuse as ctS
    #pragma unroll
    for (int jm=0;jm<4;jm++){
      #pragma unroll
      for (int nt=0;nt<3;nt++){
        int pk = nt*16 + l15;
        #pragma unroll
        for (int r=0;r<4;r++){
          int row = (w*4+jm)*16 + quad*4 + r;
          ctS[row*52 + pk] = (short)f2b(accT[jm][nt][r]);
        }
      }
    }
  }
  __syncthreads();

  // ---- softmax + aggregate: thread t = row (o,r^), loop p ----
  {
    int o = t >> 2, rr = t & 3;
    #pragma unroll
    for (int p=0;p<2;p++){
      float ct[20], vgv[20];
      #pragma unroll
      for (int q=0;q<5;q++){
        short4v cv  = *reinterpret_cast<const short4v*>(&ctS[t*52 + p*24 + q*4]);
        short4v vv4 = *reinterpret_cast<const short4v*>(&vgB[o*56 + p*24 + q*4]);
        #pragma unroll
        for (int i=0;i<4;i++){ ct[q*4+i]=b2f(cv[i]); vgv[q*4+i]=b2f(vv4[i]); }
      }
      float m = ct[0];
      #pragma unroll
      for (int k=1;k<20;k++) m = fmaxf(m, ct[k]);
      float s = 0.f, a = 0.f;
      #pragma unroll
      for (int k=0;k<20;k++){
        float e = __expf(ct[k]-m);
        s += e;
        a = fmaf(e, vgv[k], a);
      }
      aggB[(p*4+rr)*72 + o] = (short)f2b(a/s);
    }
  }
  __syncthreads();

  // ---- stage 5: conv_end (64->256) MFMA + bias + identity ----
  {
    f32x4 accE[4];
    #pragma unroll
    for (int jm=0;jm<4;jm++) accE[jm]=(f32x4)0.f;
    #pragma unroll
    for (int ks=0;ks<2;ks++){
      const int kcol = ks*32 + quad*8;
      short8 bb = *reinterpret_cast<const short8*>(&aggB[l15*72 + kcol]);
      #pragma unroll
      for (int jm=0;jm<4;jm++){
        int row = (w*4+jm)*16 + l15;
        short8 a = *reinterpret_cast<const short8*>(web + row*64 + kcol);
        accE[jm] = __builtin_amdgcn_mfma_f32_16x16x32_bf16(a, bb, accE[jm], 0,0,0);
      }
    }
    if (l15 < 8){
      int p = l15 >> 2, rr = l15 & 3;
      #pragma unroll
      for (int jm=0;jm<4;jm++){
        #pragma unroll
        for (int r=0;r<4;r++){
          int c = (w*4+jm)*16 + quad*4 + r;
          float y = accE[jm][r] + be[c] + valueT[(bN + n0 + p)*Cq + c];
          out[((size_t)(b*Cq+c))*((size_t)Nq*UPq) + (size_t)(n0+p)*UPq + rr] = y;
        }
      }
    }
  }
}

// ---------------------------------------------------------------------------
extern "C" void kernel_launch(void* const* d_in, const int* in_sizes, int n_in,
                              void* d_out, int out_size, void* d_ws, size_t ws_size,
                              hipStream_t stream)
{
  const float* pos  = (const float*)d_in[0];
  const float* key  = (const float*)d_in[1];
  const float* qry  = (const float*)d_in[2];
  const float* wv1  = (const float*)d_in[3];
  const float* bv1  = (const float*)d_in[4];
  const float* wv2  = (const float*)d_in[5];
  const float* bv2  = (const float*)d_in[6];
  const float* wvs  = (const float*)d_in[7];
  const float* bvs  = (const float*)d_in[8];
  const float* wk   = (const float*)d_in[9];
  const float* bk   = (const float*)d_in[10];
  const float* wq   = (const float*)d_in[11];
  const float* bq   = (const float*)d_in[12];
  const float* wval = (const float*)d_in[13];
  const float* bval = (const float*)d_in[14];
  const float* pw1  = (const float*)d_in[15];
  const float* pb1  = (const float*)d_in[16];
  const float* pg   = (const float*)d_in[17];
  const float* pbt  = (const float*)d_in[18];
  const float* prm  = (const float*)d_in[19];
  const float* prv  = (const float*)d_in[20];
  const float* pw2  = (const float*)d_in[21];
  const float* pb2  = (const float*)d_in[22];
  const float* aw1  = (const float*)d_in[23];
  const float* ab1  = (const float*)d_in[24];
  const float* ag   = (const float*)d_in[25];
  const float* abt  = (const float*)d_in[26];
  const float* arm  = (const float*)d_in[27];
  const float* arv  = (const float*)d_in[28];
  const float* ctw  = (const float*)d_in[29];
  const float* we   = (const float*)d_in[31];
  const float* be   = (const float*)d_in[32];

  char* ws = (char*)d_ws;
  float* valueT = (float*)(ws);                    // 8 MB fp32
  short* kfT    = (short*)(ws + 8388608);          // 1 MB bf16
  short* qfT    = (short*)(ws + 9437184);
  short* vfT    = (short*)(ws + 10485760);
  int*   idxT   = (int*)  (ws + 11534336);         // 640 KB
  short* aw1b   = (short*)(ws + 12189696);         // 32 KB
  short* ctwT   = (short*)(ws + 12222464);         // 128 KB
  short* wv1b   = (short*)(ws + 12353536);         // 256 KB
  short* wvsb   = (short*)(ws + 12615680);         // 256 KB
  short* wv2b   = (short*)(ws + 12877824);         // 128 KB
  short* wkb    = (short*)(ws + 13008896);         // 32 KB
  short* wqb    = (short*)(ws + 13041664);         // 32 KB
  short* wvalb  = (short*)(ws + 13074432);         // 32 KB
  short* pw2b   = (short*)(ws + 13107200);         // 8 KB
  short* web    = (short*)(ws + 13115392);         // 32 KB
  float* out    = (float*)d_out;

  k_prep<<<dim3(1872), dim3(256), 0, stream>>>(
      aw1, ctw, wv1, wvs, wv2, wk, wq, wval, pw2, we,
      aw1b, ctwT, wv1b, wvsb, wv2b, wkb, wqb, wvalb, pw2b, web);
  k_value<<<dim3(Bq*Nq/PTS), dim3(256), 0, stream>>>(
      key, qry, wv1b, wvsb, wv2b, wkb, wqb, wvalb,
      bv1, bv2, bvs, bk, bq, bval,
      valueT, kfT, qfT, vfT);
  k_knn<<<dim3(Bq*Nq/4), dim3(256), 0, stream>>>(pos, idxT);
  k_attn<<<dim3(Bq*Nq/2), dim3(256), 0, stream>>>(
      pos, valueT, kfT, qfT, vfT, idxT,
      pw1, pb1, pg, pbt, prm, prv, pw2b, pb2,
      aw1b, ab1, ag, abt, arm, arv, ctwT, web, be, out);
}

// Round 7
// 374.387 us; speedup vs baseline: 2.8371x; 1.2215x over previous
//
#include <hip/hip_runtime.h>
#include <hip/hip_bf16.h>

#define Bq 4
#define Nq 2048
#define Cq 256
#define Dq 64
#define UPq 4
#define KNNq 20
#define PHq 64
#define DMq 256   // D*MULT
#define PTS 16    // points per block in k_value

typedef __attribute__((ext_vector_type(8))) short short8;
typedef __attribute__((ext_vector_type(4))) short short4v;
typedef __attribute__((ext_vector_type(4))) float f32x4;
typedef __hip_bfloat16 bf16;

__device__ __forceinline__ void ld16(float* d, const float* s){
  *reinterpret_cast<float4*>(d) = *reinterpret_cast<const float4*>(s);
}
__device__ __forceinline__ unsigned short f2b(float x){
  bf16 h = __float2bfloat16(x);
  return *reinterpret_cast<unsigned short*>(&h);
}
__device__ __forceinline__ float b2f(short s){
  return __bfloat162float(*reinterpret_cast<bf16*>(&s));
}

// ---------------------------------------------------------------------------
// Kernel 0: weight prep — all bf16, row-major (straight converts) except the
// one genuine transpose ctwT.  (unchanged from round 6)
// ---------------------------------------------------------------------------
__global__ __launch_bounds__(256) void k_prep(
    const float* __restrict__ aw1, const float* __restrict__ ctw,
    const float* __restrict__ wv1, const float* __restrict__ wvs,
    const float* __restrict__ wv2, const float* __restrict__ wk,
    const float* __restrict__ wq,  const float* __restrict__ wval,
    const float* __restrict__ pw2, const float* __restrict__ we,
    short* __restrict__ aw1b, short* __restrict__ ctwT,
    short* __restrict__ wv1b, short* __restrict__ wvsb,
    short* __restrict__ wv2b, short* __restrict__ wkb,
    short* __restrict__ wqb,  short* __restrict__ wvalb,
    short* __restrict__ pw2b, short* __restrict__ web)
{
  const int t = threadIdx.x, bidx = blockIdx.x;
  if (bidx < 64){
    int i = bidx*256 + t;
    aw1b[i] = (short)f2b(aw1[i]);
  } else if (bidx < 320){
    int c = bidx - 64;
    ctwT[t*256 + c] = (short)f2b(ctw[c*256 + t]);
  } else if (bidx < 832){
    int i = (bidx-320)*256 + t;
    wv1b[i] = (short)f2b(wv1[i]);
  } else if (bidx < 1344){
    int i = (bidx-832)*256 + t;
    wvsb[i] = (short)f2b(wvs[i]);
  } else if (bidx < 1600){
    int i = (bidx-1344)*256 + t;
    wv2b[i] = (short)f2b(wv2[i]);
  } else if (bidx < 1664){
    int i = (bidx-1600)*256 + t;
    wkb[i] = (short)f2b(wk[i]);
  } else if (bidx < 1728){
    int i = (bidx-1664)*256 + t;
    wqb[i] = (short)f2b(wq[i]);
  } else if (bidx < 1792){
    int i = (bidx-1728)*256 + t;
    wvalb[i] = (short)f2b(wval[i]);
  } else if (bidx < 1808){
    int i = (bidx-1792)*256 + t;
    pw2b[i] = (short)f2b(pw2[i]);
  } else {
    int i = (bidx-1808)*256 + t;
    web[i] = (short)f2b(we[i]);
  }
}

// ---------------------------------------------------------------------------
// Kernel 1: value MLP + projections, fully MFMA (unchanged from round 6).
// ---------------------------------------------------------------------------
__global__ __launch_bounds__(256) void k_value(
    const float* __restrict__ key, const float* __restrict__ query,
    const short* __restrict__ wv1b, const short* __restrict__ wvsb,
    const short* __restrict__ wv2b, const short* __restrict__ wkb,
    const short* __restrict__ wqb,  const short* __restrict__ wvalb,
    const float* __restrict__ bv1, const float* __restrict__ bv2,
    const float* __restrict__ bvs, const float* __restrict__ bk,
    const float* __restrict__ bq,  const float* __restrict__ bval,
    float* __restrict__ valueT, short* __restrict__ kfT,
    short* __restrict__ qfT,    short* __restrict__ vfT)
{
  __shared__ __align__(16) short Xb[16*520];
  __shared__ __align__(16) short hidB[16*264];
  __shared__ __align__(16) short valB[16*264];
  __shared__ __align__(16) float valF[16*264];
  const int t = threadIdx.x;
  const int b = blockIdx.x >> 7;
  const int n0 = (blockIdx.x & 127) * PTS;
  const int lane = t & 63, quad = lane >> 4, l15 = lane & 15, w = t >> 6;

  {
    const float* kp = key   + ((size_t)(b*Cq + t))*Nq + n0;
    const float* qp = query + ((size_t)(b*Cq + t))*Nq + n0;
    float kv[16], qv[16];
    #pragma unroll
    for (int p=0;p<PTS;p+=4){ ld16(&kv[p], kp+p); ld16(&qv[p], qp+p); }
    #pragma unroll
    for (int p=0;p<PTS;p++){
      Xb[p*520 + t]       = (short)f2b(kv[p]);
      Xb[p*520 + 256 + t] = (short)f2b(qv[p]);
    }
  }
  __syncthreads();

  f32x4 acc1[4], accS[4];
  #pragma unroll
  for (int jm=0;jm<4;jm++){ acc1[jm]=(f32x4)0.f; accS[jm]=(f32x4)0.f; }

  #pragma unroll
  for (int ks=0;ks<16;ks++){
    const int kcol = ks*32 + quad*8;
    short8 xb = *reinterpret_cast<const short8*>(&Xb[l15*520 + kcol]);
    #pragma unroll
    for (int jm=0;jm<4;jm++){
      int row = (w*4+jm)*16 + l15;
      short8 a1 = *reinterpret_cast<const short8*>(wv1b + row*512 + kcol);
      short8 as = *reinterpret_cast<const short8*>(wvsb + row*512 + kcol);
      acc1[jm] = __builtin_amdgcn_mfma_f32_16x16x32_bf16(a1, xb, acc1[jm], 0,0,0);
      accS[jm] = __builtin_amdgcn_mfma_f32_16x16x32_bf16(as, xb, accS[jm], 0,0,0);
    }
  }
  #pragma unroll
  for (int jm=0;jm<4;jm++){
    #pragma unroll
    for (int r=0;r<4;r++){
      int h = (w*4+jm)*16 + quad*4 + r;
      hidB[l15*264 + h] = (short)f2b(fmaxf(acc1[jm][r] + bv1[h], 0.f));
    }
  }
  __syncthreads();

  #pragma unroll
  for (int ks=0;ks<8;ks++){
    const int kcol = ks*32 + quad*8;
    short8 hb = *reinterpret_cast<const short8*>(&hidB[l15*264 + kcol]);
    #pragma unroll
    for (int jm=0;jm<4;jm++){
      int row = (w*4+jm)*16 + l15;
      short8 a = *reinterpret_cast<const short8*>(wv2b + row*256 + kcol);
      accS[jm] = __builtin_amdgcn_mfma_f32_16x16x32_bf16(a, hb, accS[jm], 0,0,0);
    }
  }
  #pragma unroll
  for (int jm=0;jm<4;jm++){
    #pragma unroll
    for (int r=0;r<4;r++){
      int c = (w*4+jm)*16 + quad*4 + r;
      float v = accS[jm][r] + bv2[c] + bvs[c];
      valF[l15*264 + c] = v;
      valB[l15*264 + c] = (short)f2b(v);
    }
  }
  __syncthreads();

  #pragma unroll
  for (int p=0;p<PTS;p++)
    valueT[((size_t)(b*Nq + n0 + p))*Cq + t] = valF[p*264 + t];

  {
    f32x4 pk4=(f32x4)0.f, pq4=(f32x4)0.f, pv4=(f32x4)0.f;
    #pragma unroll
    for (int ks=0;ks<8;ks++){
      const int kcol = ks*32 + quad*8;
      short8 xk = *reinterpret_cast<const short8*>(&Xb[l15*520 + kcol]);
      short8 xq = *reinterpret_cast<const short8*>(&Xb[l15*520 + 256 + kcol]);
      short8 xv = *reinterpret_cast<const short8*>(&valB[l15*264 + kcol]);
      int row = w*16 + l15;
      short8 ak = *reinterpret_cast<const short8*>(wkb  + row*256 + kcol);
      short8 aq = *reinterpret_cast<const short8*>(wqb  + row*256 + kcol);
      short8 av = *reinterpret_cast<const short8*>(wvalb+ row*256 + kcol);
      pk4 = __builtin_amdgcn_mfma_f32_16x16x32_bf16(ak, xk, pk4, 0,0,0);
      pq4 = __builtin_amdgcn_mfma_f32_16x16x32_bf16(aq, xq, pq4, 0,0,0);
      pv4 = __builtin_amdgcn_mfma_f32_16x16x32_bf16(av, xv, pv4, 0,0,0);
    }
    #pragma unroll
    for (int r=0;r<4;r++){
      int o = w*16 + quad*4 + r;
      int n = n0 + l15;
      size_t base = ((size_t)(b*Nq+n))*Dq + o;
      kfT[base] = (short)f2b(pk4[r] + bk[o]);
      qfT[base] = (short)f2b(pq4[r] + bq[o]);
      vfT[base] = (short)f2b(pv4[r] + bval[o]);
    }
  }
}

// ---------------------------------------------------------------------------
// Kernel 2: KNN — wave-per-point. Distances packed into exactly-ordered f64
// keys: key = sortable_u32(dist)*2048 + j  (43 bits, exact in double;
// preserves float ordering + lowest-index tie-break). Selection = 20 rounds
// of: predicated select -> 5-level v_min_f64 tree -> 6-step shuffle min.
// Strict-successor validity (keys distinct) replaces removal marking.
// ---------------------------------------------------------------------------
__global__ __launch_bounds__(256) void k_knn(const float* __restrict__ pos,
                                             int* __restrict__ idxT)
{
  const int t = threadIdx.x;
  const int lane = t & 63;
  const int w = t >> 6;
  const int pid = blockIdx.x*4 + w;
  const int b = pid >> 11;
  const int n = pid & (Nq-1);
  const float* px = pos + (size_t)(b*3+0)*Nq;
  const float* py = pos + (size_t)(b*3+1)*Nq;
  const float* pz = pos + (size_t)(b*3+2)*Nq;
  const float xn=px[n], yn=py[n], zn=pz[n];
  const float sqn = __fadd_rn(__fadd_rn(__fmul_rn(xn,xn),__fmul_rn(yn,yn)),__fmul_rn(zn,zn));

  double kd[32];
  #pragma unroll
  for (int i=0;i<32;i++){
    int j = i*64 + lane;
    float x=px[j], y=py[j], z=pz[j];
    float sqj = __fadd_rn(__fadd_rn(__fmul_rn(x,x),__fmul_rn(y,y)),__fmul_rn(z,z));
    float dot = __fadd_rn(__fadd_rn(__fmul_rn(xn,x),__fmul_rn(yn,y)),__fmul_rn(zn,z));
    float d   = __fsub_rn(__fadd_rn(sqn,sqj), __fmul_rn(2.0f,dot));
    unsigned u = __float_as_uint(d);
    u ^= ((unsigned)((int)u >> 31)) | 0x80000000u;     // sortable uint32
    kd[i] = (double)u * 2048.0 + (double)j;            // exact 43-bit key
  }

  const double BIG = 9.0e15;
  double last = -1.0;
  for (int s=0;s<KNNq;s++){
    double c[16];
    #pragma unroll
    for (int i=0;i<16;i++){
      double a0 = (kd[i]    > last) ? kd[i]    : BIG;
      double a1 = (kd[i+16] > last) ? kd[i+16] : BIG;
      c[i] = fmin(a0, a1);
    }
    #pragma unroll
    for (int off=8; off>0; off>>=1){
      #pragma unroll
      for (int i=0;i<off;i++) c[i] = fmin(c[i], c[i+off]);
    }
    double m = c[0];
    #pragma unroll
    for (int off=1; off<64; off<<=1)
      m = fmin(m, __shfl_xor(m, off));
    if (lane == 0){
      unsigned long long kk = (unsigned long long)m;
      idxT[(size_t)pid*KNNq + s] = (int)(kk & 2047ull);
    }
    last = m;
  }
}

// ---------------------------------------------------------------------------
// Kernel 3: fused attn, P=2 points per block (unchanged from round 6).
// ---------------------------------------------------------------------------
__global__ __launch_bounds__(256) void k_attn(
  const float* __restrict__ pos,
  const float* __restrict__ valueT, const short* __restrict__ kfT,
  const short* __restrict__ qfT,    const short* __restrict__ vfT,
  const int* __restrict__ idxT,
  const float* __restrict__ pw1, const float* __restrict__ pb1,
  const float* __restrict__ pg,  const float* __restrict__ pbt,
  const float* __restrict__ prm, const float* __restrict__ prv,
  const short* __restrict__ pw2b, const float* __restrict__ pb2,
  const short* __restrict__ aw1b, const float* __restrict__ ab1,
  const float* __restrict__ ag,  const float* __restrict__ abt,
  const float* __restrict__ arm, const float* __restrict__ arv,
  const short* __restrict__ ctwT,
  const short* __restrict__ web,  const float* __restrict__ be,
  float* __restrict__ out)
{
  __shared__ __align__(16) short uT[48*72];
  __shared__ __align__(16) short sT[48*264];
  __shared__ __align__(16) char  slotA[26624];
  __shared__ __align__(16) short vgB[64*56];
  __shared__ __align__(16) short aggB[16*72];
  __shared__ float scS[DMq], sh2S[DMq];
  __shared__ float prl[3*48];
  __shared__ int   nb[48];

  short* hB  = (short*)slotA;
  short* ctS = (short*)slotA;

  const int t = threadIdx.x;
  const int b  = blockIdx.x >> 10;
  const int n0 = (blockIdx.x & 1023) * 2;
  const int lane = t & 63, quad = lane >> 4, l15 = lane & 15, w = t >> 6;
  const size_t bN = (size_t)b * Nq;

  if (t < 48){
    int p = (t >= 24);
    int k = t - p*24;
    int nn = n0 + p;
    int j = (k < KNNq) ? idxT[(bN + nn)*KNNq + k] : nn;
    nb[t] = j;
    #pragma unroll
    for (int d=0; d<3; d++){
      prl[d*48+t] = pos[((size_t)(b*3+d))*Nq + nn] - pos[((size_t)(b*3+d))*Nq + j];
    }
  }
  {
    float sc = ag[t] * rsqrtf(arv[t] + 1e-5f);
    scS[t]  = sc;
    sh2S[t] = ab1[t]*sc + (abt[t] - arm[t]*sc);
  }
  for (int i = t; i < 576; i += 256) aggB[576 + i] = 0;
  __syncthreads();

  {
    const int ph = t & 63, pkq = t >> 6;
    float sc = pg[ph] * rsqrtf(prv[ph] + 1e-5f);
    float sh = pbt[ph] - prm[ph] * sc;
    float w0 = pw1[ph*3+0], w1 = pw1[ph*3+1], w2 = pw1[ph*3+2];
    float bb = pb1[ph];
    #pragma unroll
    for (int m=0;m<12;m++){
      int pk = pkq + m*4;
      float h = w0*prl[pk] + w1*prl[48+pk] + w2*prl[96+pk] + bb;
      hB[pk*72 + ph] = (short)f2b(fmaxf(h*sc + sh, 0.f));
    }
  }
  __syncthreads();

  {
    f32x4 accP[3];
    #pragma unroll
    for (int nt=0;nt<3;nt++) accP[nt]=(f32x4)0.f;
    #pragma unroll
    for (int ks=0;ks<2;ks++){
      const int kcol = ks*32 + quad*8;
      short8 a = *reinterpret_cast<const short8*>(pw2b + (w*16+l15)*64 + kcol);
      #pragma unroll
      for (int nt=0;nt<3;nt++){
        short8 bb = *reinterpret_cast<const short8*>(&hB[(nt*16+l15)*72 + kcol]);
        accP[nt] = __builtin_amdgcn_mfma_f32_16x16x32_bf16(a, bb, accP[nt], 0,0,0);
      }
    }
    #pragma unroll
    for (int nt=0;nt<3;nt++){
      int pk = nt*16 + l15;
      int p = (pk >= 24);
      int j = nb[pk];
      int nn = n0 + p;
      #pragma unroll
      for (int r=0;r<4;r++){
        int o = w*16 + quad*4 + r;
        float pe = accP[nt][r] + pb2[o];
        float qv = b2f(qfT[(bN+nn)*Dq + o]);
        float kg = b2f(kfT[(bN+j)*Dq + o]);
        float vv = b2f(vfT[(bN+j)*Dq + o]);
        uT[pk*72 + o]  = (short)f2b((qv - kg) + pe);
        vgB[o*56 + pk] = (short)f2b(vv + pe);
      }
    }
  }
  __syncthreads();

  {
    f32x4 accC[4][3];
    #pragma unroll
    for (int jm=0;jm<4;jm++)
      #pragma unroll
      for (int nt=0;nt<3;nt++) accC[jm][nt]=(f32x4)0.f;
    #pragma unroll
    for (int ks=0;ks<2;ks++){
      const int kcol = ks*32 + quad*8;
      short8 bb[3];
      #pragma unroll
      for (int nt=0;nt<3;nt++)
        bb[nt] = *reinterpret_cast<const short8*>(&uT[(nt*16+l15)*72 + kcol]);
      #pragma unroll
      for (int jm=0;jm<4;jm++){
        int mt = w*4 + jm;
        short8 a = *reinterpret_cast<const short8*>(aw1b + (mt*16+l15)*64 + kcol);
        #pragma unroll
        for (int nt=0;nt<3;nt++)
          accC[jm][nt] = __builtin_amdgcn_mfma_f32_16x16x32_bf16(a, bb[nt], accC[jm][nt], 0,0,0);
      }
    }
    #pragma unroll
    for (int jm=0;jm<4;jm++){
      int cb = (w*4+jm)*16 + quad*4;
      #pragma unroll
      for (int nt=0;nt<3;nt++){
        int pk = nt*16 + l15;
        short4v pkv;
        #pragma unroll
        for (int r=0;r<4;r++){
          int c = cb + r;
          pkv[r] = (short)f2b(fmaxf(accC[jm][nt][r]*scS[c] + sh2S[c], 0.f));
        }
        *reinterpret_cast<short4v*>(&sT[pk*264 + cb]) = pkv;
      }
    }
  }
  __syncthreads();

  {
    f32x4 accT[4][3];
    #pragma unroll
    for (int jm=0;jm<4;jm++)
      #pragma unroll
      for (int nt=0;nt<3;nt++) accT[jm][nt]=(f32x4)0.f;
    #pragma unroll
    for (int ks=0;ks<8;ks++){
      const int kcol = ks*32 + quad*8;
      short8 bb[3];
      #pragma unroll
      for (int nt=0;nt<3;nt++)
        bb[nt] = *reinterpret_cast<const short8*>(&sT[(nt*16+l15)*264 + kcol]);
      #pragma unroll
      for (int jm=0;jm<4;jm++){
        int mt = w*4 + jm;
        short8 a = *reinterpret_cast<const short8*>(ctwT + (size_t)(mt*16+l15)*256 + kcol);
        #pragma unroll
        for (int nt=0;nt<3;nt++)
          accT[jm][nt] = __builtin_amdgcn_mfma_f32_16x16x32_bf16(a, bb[nt], accT[jm][nt], 0,0,0);
      }
    }
    __syncthreads();
    #pragma unroll
    for (int jm=0;jm<4;jm++){
      #pragma unroll
      for (int nt=0;nt<3;nt++){
        int pk = nt*16 + l15;
        #pragma unroll
        for (int r=0;r<4;r++){
          int row = (w*4+jm)*16 + quad*4 + r;
          ctS[row*52 + pk] = (short)f2b(accT[jm][nt][r]);
        }
      }
    }
  }
  __syncthreads();

  {
    int o = t >> 2, rr = t & 3;
    #pragma unroll
    for (int p=0;p<2;p++){
      float ct[20], vgv[20];
      #pragma unroll
      for (int q=0;q<5;q++){
        short4v cv  = *reinterpret_cast<const short4v*>(&ctS[t*52 + p*24 + q*4]);
        short4v vv4 = *reinterpret_cast<const short4v*>(&vgB[o*56 + p*24 + q*4]);
        #pragma unroll
        for (int i=0;i<4;i++){ ct[q*4+i]=b2f(cv[i]); vgv[q*4+i]=b2f(vv4[i]); }
      }
      float m = ct[0];
      #pragma unroll
      for (int k=1;k<20;k++) m = fmaxf(m, ct[k]);
      float s = 0.f, a = 0.f;
      #pragma unroll
      for (int k=0;k<20;k++){
        float e = __expf(ct[k]-m);
        s += e;
        a = fmaf(e, vgv[k], a);
      }
      aggB[(p*4+rr)*72 + o] = (short)f2b(a/s);
    }
  }
  __syncthreads();

  {
    f32x4 accE[4];
    #pragma unroll
    for (int jm=0;jm<4;jm++) accE[jm]=(f32x4)0.f;
    #pragma unroll
    for (int ks=0;ks<2;ks++){
      const int kcol = ks*32 + quad*8;
      short8 bb = *reinterpret_cast<const short8*>(&aggB[l15*72 + kcol]);
      #pragma unroll
      for (int jm=0;jm<4;jm++){
        int row = (w*4+jm)*16 + l15;
        short8 a = *reinterpret_cast<const short8*>(web + row*64 + kcol);
        accE[jm] = __builtin_amdgcn_mfma_f32_16x16x32_bf16(a, bb, accE[jm], 0,0,0);
      }
    }
    if (l15 < 8){
      int p = l15 >> 2, rr = l15 & 3;
      #pragma unroll
      for (int jm=0;jm<4;jm++){
        #pragma unroll
        for (int r=0;r<4;r++){
          int c = (w*4+jm)*16 + quad*4 + r;
          float y = accE[jm][r] + be[c] + valueT[(bN + n0 + p)*Cq + c];
          out[((size_t)(b*Cq+c))*((size_t)Nq*UPq) + (size_t)(n0+p)*UPq + rr] = y;
        }
      }
    }
  }
}

// ---------------------------------------------------------------------------
extern "C" void kernel_launch(void* const* d_in, const int* in_sizes, int n_in,
                              void* d_out, int out_size, void* d_ws, size_t ws_size,
                              hipStream_t stream)
{
  const float* pos  = (const float*)d_in[0];
  const float* key  = (const float*)d_in[1];
  const float* qry  = (const float*)d_in[2];
  const float* wv1  = (const float*)d_in[3];
  const float* bv1  = (const float*)d_in[4];
  const float* wv2  = (const float*)d_in[5];
  const float* bv2  = (const float*)d_in[6];
  const float* wvs  = (const float*)d_in[7];
  const float* bvs  = (const float*)d_in[8];
  const float* wk   = (const float*)d_in[9];
  const float* bk   = (const float*)d_in[10];
  const float* wq   = (const float*)d_in[11];
  const float* bq   = (const float*)d_in[12];
  const float* wval = (const float*)d_in[13];
  const float* bval = (const float*)d_in[14];
  const float* pw1  = (const float*)d_in[15];
  const float* pb1  = (const float*)d_in[16];
  const float* pg   = (const float*)d_in[17];
  const float* pbt  = (const float*)d_in[18];
  const float* prm  = (const float*)d_in[19];
  const float* prv  = (const float*)d_in[20];
  const float* pw2  = (const float*)d_in[21];
  const float* pb2  = (const float*)d_in[22];
  const float* aw1  = (const float*)d_in[23];
  const float* ab1  = (const float*)d_in[24];
  const float* ag   = (const float*)d_in[25];
  const float* abt  = (const float*)d_in[26];
  const float* arm  = (const float*)d_in[27];
  const float* arv  = (const float*)d_in[28];
  const float* ctw  = (const float*)d_in[29];
  const float* we   = (const float*)d_in[31];
  const float* be   = (const float*)d_in[32];

  char* ws = (char*)d_ws;
  float* valueT = (float*)(ws);                    // 8 MB fp32
  short* kfT    = (short*)(ws + 8388608);          // 1 MB bf16
  short* qfT    = (short*)(ws + 9437184);
  short* vfT    = (short*)(ws + 10485760);
  int*   idxT   = (int*)  (ws + 11534336);         // 640 KB
  short* aw1b   = (short*)(ws + 12189696);         // 32 KB
  short* ctwT   = (short*)(ws + 12222464);         // 128 KB
  short* wv1b   = (short*)(ws + 12353536);         // 256 KB
  short* wvsb   = (short*)(ws + 12615680);         // 256 KB
  short* wv2b   = (short*)(ws + 12877824);         // 128 KB
  short* wkb    = (short*)(ws + 13008896);         // 32 KB
  short* wqb    = (short*)(ws + 13041664);         // 32 KB
  short* wvalb  = (short*)(ws + 13074432);         // 32 KB
  short* pw2b   = (short*)(ws + 13107200);         // 8 KB
  short* web    = (short*)(ws + 13115392);         // 32 KB
  float* out    = (float*)d_out;

  k_prep<<<dim3(1872), dim3(256), 0, stream>>>(
      aw1, ctw, wv1, wvs, wv2, wk, wq, wval, pw2, we,
      aw1b, ctwT, wv1b, wvsb, wv2b, wkb, wqb, wvalb, pw2b, web);
  k_value<<<dim3(Bq*Nq/PTS), dim3(256), 0, stream>>>(
      key, qry, wv1b, wvsb, wv2b, wkb, wqb, wvalb,
      bv1, bv2, bvs, bk, bq, bval,
      valueT, kfT, qfT, vfT);
  k_knn<<<dim3(Bq*Nq/4), dim3(256), 0, stream>>>(pos, idxT);
  k_attn<<<dim3(Bq*Nq/2), dim3(256), 0, stream>>>(
      pos, valueT, kfT, qfT, vfT, idxT,
      pw1, pb1, pg, pbt, prm, prv, pw2b, pb2,
      aw1b, ab1, ag, abt, arm, arv, ctwT, web, be, out);
}

// Round 8
// 298.169 us; speedup vs baseline: 3.5624x; 1.2556x over previous
//
#include <hip/hip_runtime.h>
#include <hip/hip_bf16.h>

#define Bq 4
#define Nq 2048
#define Cq 256
#define Dq 64
#define UPq 4
#define KNNq 20
#define PHq 64
#define DMq 256   // D*MULT
#define PTS 16    // points per block in k_value

typedef __attribute__((ext_vector_type(8))) short short8;
typedef __attribute__((ext_vector_type(4))) short short4v;
typedef __attribute__((ext_vector_type(4))) float f32x4;
typedef __hip_bfloat16 bf16;

__device__ __forceinline__ void ld16(float* d, const float* s){
  *reinterpret_cast<float4*>(d) = *reinterpret_cast<const float4*>(s);
}
__device__ __forceinline__ unsigned short f2b(float x){
  bf16 h = __float2bfloat16(x);
  return *reinterpret_cast<unsigned short*>(&h);
}
__device__ __forceinline__ float b2f(short s){
  return __bfloat162float(*reinterpret_cast<bf16*>(&s));
}

// ---------------------------------------------------------------------------
// Kernel 0: weight prep — emit bf16 weights in MFMA A-fragment-swizzled order:
// dst[((mt*KS+ks)*64+lane)*8+j] = W[mt*16+(lane&15)][ks*32+(lane>>4)*8+j]
// so kernel A-loads are base + lane*16B (coalesced 1KB/wave).
// ---------------------------------------------------------------------------
__device__ __forceinline__ void swz(const float* __restrict__ src,
                                    short* __restrict__ dst,
                                    int M, int K, int g, bool transp)
{
  int j = g & 7, lane = (g >> 3) & 63, rest = g >> 9;
  int KS = K >> 5;
  int ks = rest % KS, mt = rest / KS;
  int m = mt*16 + (lane & 15);
  int k = ks*32 + ((lane >> 4) << 3) + j;
  float v = transp ? src[k*M + m] : src[m*K + k];
  dst[g] = (short)f2b(v);
}

__global__ __launch_bounds__(256) void k_prep(
    const float* __restrict__ aw1, const float* __restrict__ ctw,
    const float* __restrict__ wv1, const float* __restrict__ wvs,
    const float* __restrict__ wv2, const float* __restrict__ wk,
    const float* __restrict__ wq,  const float* __restrict__ wval,
    const float* __restrict__ pw2, const float* __restrict__ we,
    short* __restrict__ aw1b, short* __restrict__ ctwT,
    short* __restrict__ wv1b, short* __restrict__ wvsb,
    short* __restrict__ wv2b, short* __restrict__ wkb,
    short* __restrict__ wqb,  short* __restrict__ wvalb,
    short* __restrict__ pw2b, short* __restrict__ web)
{
  const int t = threadIdx.x, bidx = blockIdx.x;
  if (bidx < 512){
    swz(wv1, wv1b, 256, 512, bidx*256 + t, false);
  } else if (bidx < 1024){
    swz(wvs, wvsb, 256, 512, (bidx-512)*256 + t, false);
  } else if (bidx < 1280){
    swz(wv2, wv2b, 256, 256, (bidx-1024)*256 + t, false);
  } else if (bidx < 1344){
    swz(wk, wkb, 64, 256, (bidx-1280)*256 + t, false);
  } else if (bidx < 1408){
    swz(wq, wqb, 64, 256, (bidx-1344)*256 + t, false);
  } else if (bidx < 1472){
    swz(wval, wvalb, 64, 256, (bidx-1408)*256 + t, false);
  } else if (bidx < 1488){
    swz(pw2, pw2b, 64, 64, (bidx-1472)*256 + t, false);
  } else if (bidx < 1552){
    swz(aw1, aw1b, 256, 64, (bidx-1488)*256 + t, false);
  } else if (bidx < 1616){
    swz(we, web, 256, 64, (bidx-1552)*256 + t, false);
  } else {
    swz(ctw, ctwT, 256, 256, (bidx-1616)*256 + t, true);  // W[m=t_out][k=c] = ctw[c][t_out]
  }
}

// ---------------------------------------------------------------------------
// Kernel 1: value MLP + projections, fully MFMA; A-weights frag-swizzled.
// ---------------------------------------------------------------------------
__global__ __launch_bounds__(256) void k_value(
    const float* __restrict__ key, const float* __restrict__ query,
    const short* __restrict__ wv1b, const short* __restrict__ wvsb,
    const short* __restrict__ wv2b, const short* __restrict__ wkb,
    const short* __restrict__ wqb,  const short* __restrict__ wvalb,
    const float* __restrict__ bv1, const float* __restrict__ bv2,
    const float* __restrict__ bvs, const float* __restrict__ bk,
    const float* __restrict__ bq,  const float* __restrict__ bval,
    float* __restrict__ valueT, short* __restrict__ kfT,
    short* __restrict__ qfT,    short* __restrict__ vfT)
{
  __shared__ __align__(16) short Xb[16*520];
  __shared__ __align__(16) short hidB[16*264];
  __shared__ __align__(16) short valB[16*264];
  __shared__ __align__(16) float valF[16*264];
  const int t = threadIdx.x;
  const int b = blockIdx.x >> 7;
  const int n0 = (blockIdx.x & 127) * PTS;
  const int lane = t & 63, quad = lane >> 4, l15 = lane & 15, w = t >> 6;

  // stage X (bf16) into LDS, coalesced: 4 threads per channel, 4 passes
  {
    const int c4 = t >> 2, pq = t & 3;
    #pragma unroll
    for (int pass=0; pass<4; pass++){
      int c = pass*64 + c4;
      float4 kv = *reinterpret_cast<const float4*>(key   + ((size_t)(b*Cq+c))*Nq + n0 + pq*4);
      float4 qv = *reinterpret_cast<const float4*>(query + ((size_t)(b*Cq+c))*Nq + n0 + pq*4);
      const float* kf_ = (const float*)&kv;
      const float* qf_ = (const float*)&qv;
      #pragma unroll
      for (int i=0;i<4;i++){
        Xb[(pq*4+i)*520 + c]       = (short)f2b(kf_[i]);
        Xb[(pq*4+i)*520 + 256 + c] = (short)f2b(qf_[i]);
      }
    }
  }
  __syncthreads();

  f32x4 acc1[4], accS[4];
  #pragma unroll
  for (int jm=0;jm<4;jm++){ acc1[jm]=(f32x4)0.f; accS[jm]=(f32x4)0.f; }

  // conv1 (512->256) + shortcut; A frag-swizzled (KS=16)
  #pragma unroll
  for (int ks=0;ks<16;ks++){
    const int kcol = ks*32 + quad*8;
    short8 xb = *reinterpret_cast<const short8*>(&Xb[l15*520 + kcol]);
    #pragma unroll
    for (int jm=0;jm<4;jm++){
      int mt = w*4 + jm;
      short8 a1 = *reinterpret_cast<const short8*>(wv1b + ((mt*16+ks)*64 + lane)*8);
      short8 as = *reinterpret_cast<const short8*>(wvsb + ((mt*16+ks)*64 + lane)*8);
      acc1[jm] = __builtin_amdgcn_mfma_f32_16x16x32_bf16(a1, xb, acc1[jm], 0,0,0);
      accS[jm] = __builtin_amdgcn_mfma_f32_16x16x32_bf16(as, xb, accS[jm], 0,0,0);
    }
  }
  #pragma unroll
  for (int jm=0;jm<4;jm++){
    #pragma unroll
    for (int r=0;r<4;r++){
      int h = (w*4+jm)*16 + quad*4 + r;
      hidB[l15*264 + h] = (short)f2b(fmaxf(acc1[jm][r] + bv1[h], 0.f));
    }
  }
  __syncthreads();

  // wv2 (256->256) accumulating into shortcut acc (KS=8)
  #pragma unroll
  for (int ks=0;ks<8;ks++){
    const int kcol = ks*32 + quad*8;
    short8 hb = *reinterpret_cast<const short8*>(&hidB[l15*264 + kcol]);
    #pragma unroll
    for (int jm=0;jm<4;jm++){
      int mt = w*4 + jm;
      short8 a = *reinterpret_cast<const short8*>(wv2b + ((mt*8+ks)*64 + lane)*8);
      accS[jm] = __builtin_amdgcn_mfma_f32_16x16x32_bf16(a, hb, accS[jm], 0,0,0);
    }
  }
  #pragma unroll
  for (int jm=0;jm<4;jm++){
    #pragma unroll
    for (int r=0;r<4;r++){
      int c = (w*4+jm)*16 + quad*4 + r;
      float v = accS[jm][r] + bv2[c] + bvs[c];
      valF[l15*264 + c] = v;
      valB[l15*264 + c] = (short)f2b(v);
    }
  }
  __syncthreads();

  #pragma unroll
  for (int p=0;p<PTS;p++)
    valueT[((size_t)(b*Nq + n0 + p))*Cq + t] = valF[p*264 + t];

  // projections (M=64, KS=8); A frag-swizzled, stores short4-vectorized
  {
    f32x4 pk4=(f32x4)0.f, pq4=(f32x4)0.f, pv4=(f32x4)0.f;
    #pragma unroll
    for (int ks=0;ks<8;ks++){
      const int kcol = ks*32 + quad*8;
      short8 xk = *reinterpret_cast<const short8*>(&Xb[l15*520 + kcol]);
      short8 xq = *reinterpret_cast<const short8*>(&Xb[l15*520 + 256 + kcol]);
      short8 xv = *reinterpret_cast<const short8*>(&valB[l15*264 + kcol]);
      short8 ak = *reinterpret_cast<const short8*>(wkb  + ((w*8+ks)*64 + lane)*8);
      short8 aq = *reinterpret_cast<const short8*>(wqb  + ((w*8+ks)*64 + lane)*8);
      short8 av = *reinterpret_cast<const short8*>(wvalb+ ((w*8+ks)*64 + lane)*8);
      pk4 = __builtin_amdgcn_mfma_f32_16x16x32_bf16(ak, xk, pk4, 0,0,0);
      pq4 = __builtin_amdgcn_mfma_f32_16x16x32_bf16(aq, xq, pq4, 0,0,0);
      pv4 = __builtin_amdgcn_mfma_f32_16x16x32_bf16(av, xv, pv4, 0,0,0);
    }
    short4v ok, oq, ov;
    #pragma unroll
    for (int r=0;r<4;r++){
      int o = w*16 + quad*4 + r;
      ok[r] = (short)f2b(pk4[r] + bk[o]);
      oq[r] = (short)f2b(pq4[r] + bq[o]);
      ov[r] = (short)f2b(pv4[r] + bval[o]);
    }
    int n = n0 + l15;
    size_t base = ((size_t)(b*Nq+n))*Dq + w*16 + quad*4;
    *reinterpret_cast<short4v*>(kfT + base) = ok;
    *reinterpret_cast<short4v*>(qfT + base) = oq;
    *reinterpret_cast<short4v*>(vfT + base) = ov;
  }
}

// ---------------------------------------------------------------------------
// Kernel 2: KNN — wave-per-point, f64-key tournament (unchanged from r7).
// ---------------------------------------------------------------------------
__global__ __launch_bounds__(256) void k_knn(const float* __restrict__ pos,
                                             int* __restrict__ idxT)
{
  const int t = threadIdx.x;
  const int lane = t & 63;
  const int w = t >> 6;
  const int pid = blockIdx.x*4 + w;
  const int b = pid >> 11;
  const int n = pid & (Nq-1);
  const float* px = pos + (size_t)(b*3+0)*Nq;
  const float* py = pos + (size_t)(b*3+1)*Nq;
  const float* pz = pos + (size_t)(b*3+2)*Nq;
  const float xn=px[n], yn=py[n], zn=pz[n];
  const float sqn = __fadd_rn(__fadd_rn(__fmul_rn(xn,xn),__fmul_rn(yn,yn)),__fmul_rn(zn,zn));

  double kd[32];
  #pragma unroll
  for (int i=0;i<32;i++){
    int j = i*64 + lane;
    float x=px[j], y=py[j], z=pz[j];
    float sqj = __fadd_rn(__fadd_rn(__fmul_rn(x,x),__fmul_rn(y,y)),__fmul_rn(z,z));
    float dot = __fadd_rn(__fadd_rn(__fmul_rn(xn,x),__fmul_rn(yn,y)),__fmul_rn(zn,z));
    float d   = __fsub_rn(__fadd_rn(sqn,sqj), __fmul_rn(2.0f,dot));
    unsigned u = __float_as_uint(d);
    u ^= ((unsigned)((int)u >> 31)) | 0x80000000u;
    kd[i] = (double)u * 2048.0 + (double)j;
  }

  const double BIG = 9.0e15;
  double last = -1.0;
  for (int s=0;s<KNNq;s++){
    double c[16];
    #pragma unroll
    for (int i=0;i<16;i++){
      double a0 = (kd[i]    > last) ? kd[i]    : BIG;
      double a1 = (kd[i+16] > last) ? kd[i+16] : BIG;
      c[i] = fmin(a0, a1);
    }
    #pragma unroll
    for (int off=8; off>0; off>>=1){
      #pragma unroll
      for (int i=0;i<off;i++) c[i] = fmin(c[i], c[i+off]);
    }
    double m = c[0];
    #pragma unroll
    for (int off=1; off<64; off<<=1)
      m = fmin(m, __shfl_xor(m, off));
    if (lane == 0){
      unsigned long long kk = (unsigned long long)m;
      idxT[(size_t)pid*KNNq + s] = (int)(kk & 2047ull);
    }
    last = m;
  }
}

// ---------------------------------------------------------------------------
// Kernel 3: fused attn, P=2 points per block; A-weights frag-swizzled;
// short4 gathers for kf/qf/vf.
// ---------------------------------------------------------------------------
__global__ __launch_bounds__(256) void k_attn(
  const float* __restrict__ pos,
  const float* __restrict__ valueT, const short* __restrict__ kfT,
  const short* __restrict__ qfT,    const short* __restrict__ vfT,
  const int* __restrict__ idxT,
  const float* __restrict__ pw1, const float* __restrict__ pb1,
  const float* __restrict__ pg,  const float* __restrict__ pbt,
  const float* __restrict__ prm, const float* __restrict__ prv,
  const short* __restrict__ pw2b, const float* __restrict__ pb2,
  const short* __restrict__ aw1b, const float* __restrict__ ab1,
  const float* __restrict__ ag,  const float* __restrict__ abt,
  const float* __restrict__ arm, const float* __restrict__ arv,
  const short* __restrict__ ctwT,
  const short* __restrict__ web,  const float* __restrict__ be,
  float* __restrict__ out)
{
  __shared__ __align__(16) short uT[48*72];
  __shared__ __align__(16) short sT[48*264];
  __shared__ __align__(16) char  slotA[26624];
  __shared__ __align__(16) short vgB[64*56];
  __shared__ __align__(16) short aggB[16*72];
  __shared__ float scS[DMq], sh2S[DMq];
  __shared__ float prl[3*48];
  __shared__ int   nb[48];

  short* hB  = (short*)slotA;
  short* ctS = (short*)slotA;

  const int t = threadIdx.x;
  const int b  = blockIdx.x >> 10;
  const int n0 = (blockIdx.x & 1023) * 2;
  const int lane = t & 63, quad = lane >> 4, l15 = lane & 15, w = t >> 6;
  const size_t bN = (size_t)b * Nq;

  if (t < 48){
    int p = (t >= 24);
    int k = t - p*24;
    int nn = n0 + p;
    int j = (k < KNNq) ? idxT[(bN + nn)*KNNq + k] : nn;
    nb[t] = j;
    #pragma unroll
    for (int d=0; d<3; d++){
      prl[d*48+t] = pos[((size_t)(b*3+d))*Nq + nn] - pos[((size_t)(b*3+d))*Nq + j];
    }
  }
  {
    float sc = ag[t] * rsqrtf(arv[t] + 1e-5f);
    scS[t]  = sc;
    sh2S[t] = ab1[t]*sc + (abt[t] - arm[t]*sc);
  }
  for (int i = t; i < 576; i += 256) aggB[576 + i] = 0;
  __syncthreads();

  {
    const int ph = t & 63, pkq = t >> 6;
    float sc = pg[ph] * rsqrtf(prv[ph] + 1e-5f);
    float sh = pbt[ph] - prm[ph] * sc;
    float w0 = pw1[ph*3+0], w1 = pw1[ph*3+1], w2 = pw1[ph*3+2];
    float bb = pb1[ph];
    #pragma unroll
    for (int m=0;m<12;m++){
      int pk = pkq + m*4;
      float h = w0*prl[pk] + w1*prl[48+pk] + w2*prl[96+pk] + bb;
      hB[pk*72 + ph] = (short)f2b(fmaxf(h*sc + sh, 0.f));
    }
  }
  __syncthreads();

  // ---- stage 2: pos_emb via MFMA (KS=2); epilogue builds uT, vgB ----
  {
    f32x4 accP[3];
    #pragma unroll
    for (int nt=0;nt<3;nt++) accP[nt]=(f32x4)0.f;
    #pragma unroll
    for (int ks=0;ks<2;ks++){
      const int kcol = ks*32 + quad*8;
      short8 a = *reinterpret_cast<const short8*>(pw2b + ((w*2+ks)*64 + lane)*8);
      #pragma unroll
      for (int nt=0;nt<3;nt++){
        short8 bb = *reinterpret_cast<const short8*>(&hB[(nt*16+l15)*72 + kcol]);
        accP[nt] = __builtin_amdgcn_mfma_f32_16x16x32_bf16(a, bb, accP[nt], 0,0,0);
      }
    }
    const int obase = w*16 + quad*4;
    #pragma unroll
    for (int nt=0;nt<3;nt++){
      int pk = nt*16 + l15;
      int p = (pk >= 24);
      int j = nb[pk];
      int nn = n0 + p;
      short4v q4 = *reinterpret_cast<const short4v*>(qfT + (bN+nn)*Dq + obase);
      short4v k4 = *reinterpret_cast<const short4v*>(kfT + (bN+j)*Dq + obase);
      short4v v4 = *reinterpret_cast<const short4v*>(vfT + (bN+j)*Dq + obase);
      #pragma unroll
      for (int r=0;r<4;r++){
        int o = obase + r;
        float pe = accP[nt][r] + pb2[o];
        uT[pk*72 + o]  = (short)f2b((b2f(q4[r]) - b2f(k4[r])) + pe);
        vgB[o*56 + pk] = (short)f2b(b2f(v4[r]) + pe);
      }
    }
  }
  __syncthreads();

  // ---- stage 3: attn conv1 (64->256) MFMA (KS=2); bn+relu -> sT ----
  {
    f32x4 accC[4][3];
    #pragma unroll
    for (int jm=0;jm<4;jm++)
      #pragma unroll
      for (int nt=0;nt<3;nt++) accC[jm][nt]=(f32x4)0.f;
    #pragma unroll
    for (int ks=0;ks<2;ks++){
      const int kcol = ks*32 + quad*8;
      short8 bb[3];
      #pragma unroll
      for (int nt=0;nt<3;nt++)
        bb[nt] = *reinterpret_cast<const short8*>(&uT[(nt*16+l15)*72 + kcol]);
      #pragma unroll
      for (int jm=0;jm<4;jm++){
        int mt = w*4 + jm;
        short8 a = *reinterpret_cast<const short8*>(aw1b + ((mt*2+ks)*64 + lane)*8);
        #pragma unroll
        for (int nt=0;nt<3;nt++)
          accC[jm][nt] = __builtin_amdgcn_mfma_f32_16x16x32_bf16(a, bb[nt], accC[jm][nt], 0,0,0);
      }
    }
    #pragma unroll
    for (int jm=0;jm<4;jm++){
      int cb = (w*4+jm)*16 + quad*4;
      #pragma unroll
      for (int nt=0;nt<3;nt++){
        int pk = nt*16 + l15;
        short4v pkv;
        #pragma unroll
        for (int r=0;r<4;r++){
          int c = cb + r;
          pkv[r] = (short)f2b(fmaxf(accC[jm][nt][r]*scS[c] + sh2S[c], 0.f));
        }
        *reinterpret_cast<short4v*>(&sT[pk*264 + cb]) = pkv;
      }
    }
  }
  __syncthreads();

  // ---- stage 4: convT (256->256) MFMA (KS=8); ct -> ctS ----
  {
    f32x4 accT[4][3];
    #pragma unroll
    for (int jm=0;jm<4;jm++)
      #pragma unroll
      for (int nt=0;nt<3;nt++) accT[jm][nt]=(f32x4)0.f;
    #pragma unroll
    for (int ks=0;ks<8;ks++){
      const int kcol = ks*32 + quad*8;
      short8 bb[3];
      #pragma unroll
      for (int nt=0;nt<3;nt++)
        bb[nt] = *reinterpret_cast<const short8*>(&sT[(nt*16+l15)*264 + kcol]);
      #pragma unroll
      for (int jm=0;jm<4;jm++){
        int mt = w*4 + jm;
        short8 a = *reinterpret_cast<const short8*>(ctwT + ((mt*8+ks)*64 + lane)*8);
        #pragma unroll
        for (int nt=0;nt<3;nt++)
          accT[jm][nt] = __builtin_amdgcn_mfma_f32_16x16x32_bf16(a, bb[nt], accT[jm][nt], 0,0,0);
      }
    }
    __syncthreads();
    #pragma unroll
    for (int jm=0;jm<4;jm++){
      #pragma unroll
      for (int nt=0;nt<3;nt++){
        int pk = nt*16 + l15;
        #pragma unroll
        for (int r=0;r<4;r++){
          int row = (w*4+jm)*16 + quad*4 + r;
          ctS[row*52 + pk] = (short)f2b(accT[jm][nt][r]);
        }
      }
    }
  }
  __syncthreads();

  {
    int o = t >> 2, rr = t & 3;
    #pragma unroll
    for (int p=0;p<2;p++){
      float ct[20], vgv[20];
      #pragma unroll
      for (int q=0;q<5;q++){
        short4v cv  = *reinterpret_cast<const short4v*>(&ctS[t*52 + p*24 + q*4]);
        short4v vv4 = *reinterpret_cast<const short4v*>(&vgB[o*56 + p*24 + q*4]);
        #pragma unroll
        for (int i=0;i<4;i++){ ct[q*4+i]=b2f(cv[i]); vgv[q*4+i]=b2f(vv4[i]); }
      }
      float m = ct[0];
      #pragma unroll
      for (int k=1;k<20;k++) m = fmaxf(m, ct[k]);
      float s = 0.f, a = 0.f;
      #pragma unroll
      for (int k=0;k<20;k++){
        float e = __expf(ct[k]-m);
        s += e;
        a = fmaf(e, vgv[k], a);
      }
      aggB[(p*4+rr)*72 + o] = (short)f2b(a/s);
    }
  }
  __syncthreads();

  // ---- stage 5: conv_end (64->256) MFMA (KS=2) + bias + identity ----
  {
    f32x4 accE[4];
    #pragma unroll
    for (int jm=0;jm<4;jm++) accE[jm]=(f32x4)0.f;
    #pragma unroll
    for (int ks=0;ks<2;ks++){
      const int kcol = ks*32 + quad*8;
      short8 bb = *reinterpret_cast<const short8*>(&aggB[l15*72 + kcol]);
      #pragma unroll
      for (int jm=0;jm<4;jm++){
        int mt = w*4 + jm;
        short8 a = *reinterpret_cast<const short8*>(web + ((mt*2+ks)*64 + lane)*8);
        accE[jm] = __builtin_amdgcn_mfma_f32_16x16x32_bf16(a, bb, accE[jm], 0,0,0);
      }
    }
    if (l15 < 8){
      int p = l15 >> 2, rr = l15 & 3;
      #pragma unroll
      for (int jm=0;jm<4;jm++){
        #pragma unroll
        for (int r=0;r<4;r++){
          int c = (w*4+jm)*16 + quad*4 + r;
          float y = accE[jm][r] + be[c] + valueT[(bN + n0 + p)*Cq + c];
          out[((size_t)(b*Cq+c))*((size_t)Nq*UPq) + (size_t)(n0+p)*UPq + rr] = y;
        }
      }
    }
  }
}

// ---------------------------------------------------------------------------
extern "C" void kernel_launch(void* const* d_in, const int* in_sizes, int n_in,
                              void* d_out, int out_size, void* d_ws, size_t ws_size,
                              hipStream_t stream)
{
  const float* pos  = (const float*)d_in[0];
  const float* key  = (const float*)d_in[1];
  const float* qry  = (const float*)d_in[2];
  const float* wv1  = (const float*)d_in[3];
  const float* bv1  = (const float*)d_in[4];
  const float* wv2  = (const float*)d_in[5];
  const float* bv2  = (const float*)d_in[6];
  const float* wvs  = (const float*)d_in[7];
  const float* bvs  = (const float*)d_in[8];
  const float* wk   = (const float*)d_in[9];
  const float* bk   = (const float*)d_in[10];
  const float* wq   = (const float*)d_in[11];
  const float* bq   = (const float*)d_in[12];
  const float* wval = (const float*)d_in[13];
  const float* bval = (const float*)d_in[14];
  const float* pw1  = (const float*)d_in[15];
  const float* pb1  = (const float*)d_in[16];
  const float* pg   = (const float*)d_in[17];
  const float* pbt  = (const float*)d_in[18];
  const float* prm  = (const float*)d_in[19];
  const float* prv  = (const float*)d_in[20];
  const float* pw2  = (const float*)d_in[21];
  const float* pb2  = (const float*)d_in[22];
  const float* aw1  = (const float*)d_in[23];
  const float* ab1  = (const float*)d_in[24];
  const float* ag   = (const float*)d_in[25];
  const float* abt  = (const float*)d_in[26];
  const float* arm  = (const float*)d_in[27];
  const float* arv  = (const float*)d_in[28];
  const float* ctw  = (const float*)d_in[29];
  const float* we   = (const float*)d_in[31];
  const float* be   = (const float*)d_in[32];

  char* ws = (char*)d_ws;
  float* valueT = (float*)(ws);                    // 8 MB fp32
  short* kfT    = (short*)(ws + 8388608);          // 1 MB bf16
  short* qfT    = (short*)(ws + 9437184);
  short* vfT    = (short*)(ws + 10485760);
  int*   idxT   = (int*)  (ws + 11534336);         // 640 KB
  short* aw1b   = (short*)(ws + 12189696);         // 32 KB
  short* ctwT   = (short*)(ws + 12222464);         // 128 KB
  short* wv1b   = (short*)(ws + 12353536);         // 256 KB
  short* wvsb   = (short*)(ws + 12615680);         // 256 KB
  short* wv2b   = (short*)(ws + 12877824);         // 128 KB
  short* wkb    = (short*)(ws + 13008896);         // 32 KB
  short* wqb    = (short*)(ws + 13041664);         // 32 KB
  short* wvalb  = (short*)(ws + 13074432);         // 32 KB
  short* pw2b   = (short*)(ws + 13107200);         // 8 KB
  short* web    = (short*)(ws + 13115392);         // 32 KB
  float* out    = (float*)d_out;

  k_prep<<<dim3(1872), dim3(256), 0, stream>>>(
      aw1, ctw, wv1, wvs, wv2, wk, wq, wval, pw2, we,
      aw1b, ctwT, wv1b, wvsb, wv2b, wkb, wqb, wvalb, pw2b, web);
  k_value<<<dim3(Bq*Nq/PTS), dim3(256), 0, stream>>>(
      key, qry, wv1b, wvsb, wv2b, wkb, wqb, wvalb,
      bv1, bv2, bvs, bk, bq, bval,
      valueT, kfT, qfT, vfT);
  k_knn<<<dim3(Bq*Nq/4), dim3(256), 0, stream>>>(pos, idxT);
  k_attn<<<dim3(Bq*Nq/2), dim3(256), 0, stream>>>(
      pos, valueT, kfT, qfT, vfT, idxT,
      pw1, pb1, pg, pbt, prm, prv, pw2b, pb2,
      aw1b, ab1, ag, abt, arm, arv, ctwT, web, be, out);
}

// Round 9
// 287.494 us; speedup vs baseline: 3.6946x; 1.0371x over previous
//
#include <hip/hip_runtime.h>
#include <hip/hip_bf16.h>

#define Bq 4
#define Nq 2048
#define Cq 256
#define Dq 64
#define UPq 4
#define KNNq 20
#define PHq 64
#define DMq 256   // D*MULT
#define PTS 16    // points per block in k_value

typedef __attribute__((ext_vector_type(8))) short short8;
typedef __attribute__((ext_vector_type(4))) short short4v;
typedef __attribute__((ext_vector_type(4))) float f32x4;
typedef __hip_bfloat16 bf16;

__device__ __forceinline__ void ld16(float* d, const float* s){
  *reinterpret_cast<float4*>(d) = *reinterpret_cast<const float4*>(s);
}
__device__ __forceinline__ unsigned short f2b(float x){
  bf16 h = __float2bfloat16(x);
  return *reinterpret_cast<unsigned short*>(&h);
}
__device__ __forceinline__ float b2f(short s){
  return __bfloat162float(*reinterpret_cast<bf16*>(&s));
}

// ---------------------------------------------------------------------------
// Kernel 0: weight prep — emit bf16 weights in MFMA A-fragment-swizzled order:
// dst[((mt*KS+ks)*64+lane)*8+j] = W[mt*16+(lane&15)][ks*32+(lane>>4)*8+j]
// so kernel A-loads are base + lane*16B (coalesced 1KB/wave).
// ---------------------------------------------------------------------------
__device__ __forceinline__ void swz(const float* __restrict__ src,
                                    short* __restrict__ dst,
                                    int M, int K, int g, bool transp)
{
  int j = g & 7, lane = (g >> 3) & 63, rest = g >> 9;
  int KS = K >> 5;
  int ks = rest % KS, mt = rest / KS;
  int m = mt*16 + (lane & 15);
  int k = ks*32 + ((lane >> 4) << 3) + j;
  float v = transp ? src[k*M + m] : src[m*K + k];
  dst[g] = (short)f2b(v);
}

__global__ __launch_bounds__(256) void k_prep(
    const float* __restrict__ aw1, const float* __restrict__ ctw,
    const float* __restrict__ wv1, const float* __restrict__ wvs,
    const float* __restrict__ wv2, const float* __restrict__ wk,
    const float* __restrict__ wq,  const float* __restrict__ wval,
    const float* __restrict__ pw2, const float* __restrict__ we,
    short* __restrict__ aw1b, short* __restrict__ ctwT,
    short* __restrict__ wv1b, short* __restrict__ wvsb,
    short* __restrict__ wv2b, short* __restrict__ wkb,
    short* __restrict__ wqb,  short* __restrict__ wvalb,
    short* __restrict__ pw2b, short* __restrict__ web)
{
  const int t = threadIdx.x, bidx = blockIdx.x;
  if (bidx < 512){
    swz(wv1, wv1b, 256, 512, bidx*256 + t, false);
  } else if (bidx < 1024){
    swz(wvs, wvsb, 256, 512, (bidx-512)*256 + t, false);
  } else if (bidx < 1280){
    swz(wv2, wv2b, 256, 256, (bidx-1024)*256 + t, false);
  } else if (bidx < 1344){
    swz(wk, wkb, 64, 256, (bidx-1280)*256 + t, false);
  } else if (bidx < 1408){
    swz(wq, wqb, 64, 256, (bidx-1344)*256 + t, false);
  } else if (bidx < 1472){
    swz(wval, wvalb, 64, 256, (bidx-1408)*256 + t, false);
  } else if (bidx < 1488){
    swz(pw2, pw2b, 64, 64, (bidx-1472)*256 + t, false);
  } else if (bidx < 1552){
    swz(aw1, aw1b, 256, 64, (bidx-1488)*256 + t, false);
  } else if (bidx < 1616){
    swz(we, web, 256, 64, (bidx-1552)*256 + t, false);
  } else {
    swz(ctw, ctwT, 256, 256, (bidx-1616)*256 + t, true);  // W[m=t_out][k=c] = ctw[c][t_out]
  }
}

// ---------------------------------------------------------------------------
// Kernel 1: value MLP + projections, fully MFMA; A-weights frag-swizzled.
// (unchanged from round 8)
// ---------------------------------------------------------------------------
__global__ __launch_bounds__(256) void k_value(
    const float* __restrict__ key, const float* __restrict__ query,
    const short* __restrict__ wv1b, const short* __restrict__ wvsb,
    const short* __restrict__ wv2b, const short* __restrict__ wkb,
    const short* __restrict__ wqb,  const short* __restrict__ wvalb,
    const float* __restrict__ bv1, const float* __restrict__ bv2,
    const float* __restrict__ bvs, const float* __restrict__ bk,
    const float* __restrict__ bq,  const float* __restrict__ bval,
    float* __restrict__ valueT, short* __restrict__ kfT,
    short* __restrict__ qfT,    short* __restrict__ vfT)
{
  __shared__ __align__(16) short Xb[16*520];
  __shared__ __align__(16) short hidB[16*264];
  __shared__ __align__(16) short valB[16*264];
  __shared__ __align__(16) float valF[16*264];
  const int t = threadIdx.x;
  const int b = blockIdx.x >> 7;
  const int n0 = (blockIdx.x & 127) * PTS;
  const int lane = t & 63, quad = lane >> 4, l15 = lane & 15, w = t >> 6;

  {
    const int c4 = t >> 2, pq = t & 3;
    #pragma unroll
    for (int pass=0; pass<4; pass++){
      int c = pass*64 + c4;
      float4 kv = *reinterpret_cast<const float4*>(key   + ((size_t)(b*Cq+c))*Nq + n0 + pq*4);
      float4 qv = *reinterpret_cast<const float4*>(query + ((size_t)(b*Cq+c))*Nq + n0 + pq*4);
      const float* kf_ = (const float*)&kv;
      const float* qf_ = (const float*)&qv;
      #pragma unroll
      for (int i=0;i<4;i++){
        Xb[(pq*4+i)*520 + c]       = (short)f2b(kf_[i]);
        Xb[(pq*4+i)*520 + 256 + c] = (short)f2b(qf_[i]);
      }
    }
  }
  __syncthreads();

  f32x4 acc1[4], accS[4];
  #pragma unroll
  for (int jm=0;jm<4;jm++){ acc1[jm]=(f32x4)0.f; accS[jm]=(f32x4)0.f; }

  #pragma unroll
  for (int ks=0;ks<16;ks++){
    const int kcol = ks*32 + quad*8;
    short8 xb = *reinterpret_cast<const short8*>(&Xb[l15*520 + kcol]);
    #pragma unroll
    for (int jm=0;jm<4;jm++){
      int mt = w*4 + jm;
      short8 a1 = *reinterpret_cast<const short8*>(wv1b + ((mt*16+ks)*64 + lane)*8);
      short8 as = *reinterpret_cast<const short8*>(wvsb + ((mt*16+ks)*64 + lane)*8);
      acc1[jm] = __builtin_amdgcn_mfma_f32_16x16x32_bf16(a1, xb, acc1[jm], 0,0,0);
      accS[jm] = __builtin_amdgcn_mfma_f32_16x16x32_bf16(as, xb, accS[jm], 0,0,0);
    }
  }
  #pragma unroll
  for (int jm=0;jm<4;jm++){
    #pragma unroll
    for (int r=0;r<4;r++){
      int h = (w*4+jm)*16 + quad*4 + r;
      hidB[l15*264 + h] = (short)f2b(fmaxf(acc1[jm][r] + bv1[h], 0.f));
    }
  }
  __syncthreads();

  #pragma unroll
  for (int ks=0;ks<8;ks++){
    const int kcol = ks*32 + quad*8;
    short8 hb = *reinterpret_cast<const short8*>(&hidB[l15*264 + kcol]);
    #pragma unroll
    for (int jm=0;jm<4;jm++){
      int mt = w*4 + jm;
      short8 a = *reinterpret_cast<const short8*>(wv2b + ((mt*8+ks)*64 + lane)*8);
      accS[jm] = __builtin_amdgcn_mfma_f32_16x16x32_bf16(a, hb, accS[jm], 0,0,0);
    }
  }
  #pragma unroll
  for (int jm=0;jm<4;jm++){
    #pragma unroll
    for (int r=0;r<4;r++){
      int c = (w*4+jm)*16 + quad*4 + r;
      float v = accS[jm][r] + bv2[c] + bvs[c];
      valF[l15*264 + c] = v;
      valB[l15*264 + c] = (short)f2b(v);
    }
  }
  __syncthreads();

  #pragma unroll
  for (int p=0;p<PTS;p++)
    valueT[((size_t)(b*Nq + n0 + p))*Cq + t] = valF[p*264 + t];

  {
    f32x4 pk4=(f32x4)0.f, pq4=(f32x4)0.f, pv4=(f32x4)0.f;
    #pragma unroll
    for (int ks=0;ks<8;ks++){
      const int kcol = ks*32 + quad*8;
      short8 xk = *reinterpret_cast<const short8*>(&Xb[l15*520 + kcol]);
      short8 xq = *reinterpret_cast<const short8*>(&Xb[l15*520 + 256 + kcol]);
      short8 xv = *reinterpret_cast<const short8*>(&valB[l15*264 + kcol]);
      short8 ak = *reinterpret_cast<const short8*>(wkb  + ((w*8+ks)*64 + lane)*8);
      short8 aq = *reinterpret_cast<const short8*>(wqb  + ((w*8+ks)*64 + lane)*8);
      short8 av = *reinterpret_cast<const short8*>(wvalb+ ((w*8+ks)*64 + lane)*8);
      pk4 = __builtin_amdgcn_mfma_f32_16x16x32_bf16(ak, xk, pk4, 0,0,0);
      pq4 = __builtin_amdgcn_mfma_f32_16x16x32_bf16(aq, xq, pq4, 0,0,0);
      pv4 = __builtin_amdgcn_mfma_f32_16x16x32_bf16(av, xv, pv4, 0,0,0);
    }
    short4v ok, oq, ov;
    #pragma unroll
    for (int r=0;r<4;r++){
      int o = w*16 + quad*4 + r;
      ok[r] = (short)f2b(pk4[r] + bk[o]);
      oq[r] = (short)f2b(pq4[r] + bq[o]);
      ov[r] = (short)f2b(pv4[r] + bval[o]);
    }
    int n = n0 + l15;
    size_t base = ((size_t)(b*Nq+n))*Dq + w*16 + quad*4;
    *reinterpret_cast<short4v*>(kfT + base) = ok;
    *reinterpret_cast<short4v*>(qfT + base) = oq;
    *reinterpret_cast<short4v*>(vfT + base) = ov;
  }
}

// ---------------------------------------------------------------------------
// Kernel 2: KNN — wave-per-point, f64-key tournament (unchanged from r7).
// ---------------------------------------------------------------------------
__global__ __launch_bounds__(256) void k_knn(const float* __restrict__ pos,
                                             int* __restrict__ idxT)
{
  const int t = threadIdx.x;
  const int lane = t & 63;
  const int w = t >> 6;
  const int pid = blockIdx.x*4 + w;
  const int b = pid >> 11;
  const int n = pid & (Nq-1);
  const float* px = pos + (size_t)(b*3+0)*Nq;
  const float* py = pos + (size_t)(b*3+1)*Nq;
  const float* pz = pos + (size_t)(b*3+2)*Nq;
  const float xn=px[n], yn=py[n], zn=pz[n];
  const float sqn = __fadd_rn(__fadd_rn(__fmul_rn(xn,xn),__fmul_rn(yn,yn)),__fmul_rn(zn,zn));

  double kd[32];
  #pragma unroll
  for (int i=0;i<32;i++){
    int j = i*64 + lane;
    float x=px[j], y=py[j], z=pz[j];
    float sqj = __fadd_rn(__fadd_rn(__fmul_rn(x,x),__fmul_rn(y,y)),__fmul_rn(z,z));
    float dot = __fadd_rn(__fadd_rn(__fmul_rn(xn,x),__fmul_rn(yn,y)),__fmul_rn(zn,z));
    float d   = __fsub_rn(__fadd_rn(sqn,sqj), __fmul_rn(2.0f,dot));
    unsigned u = __float_as_uint(d);
    u ^= ((unsigned)((int)u >> 31)) | 0x80000000u;
    kd[i] = (double)u * 2048.0 + (double)j;
  }

  const double BIG = 9.0e15;
  double last = -1.0;
  for (int s=0;s<KNNq;s++){
    double c[16];
    #pragma unroll
    for (int i=0;i<16;i++){
      double a0 = (kd[i]    > last) ? kd[i]    : BIG;
      double a1 = (kd[i+16] > last) ? kd[i+16] : BIG;
      c[i] = fmin(a0, a1);
    }
    #pragma unroll
    for (int off=8; off>0; off>>=1){
      #pragma unroll
      for (int i=0;i<off;i++) c[i] = fmin(c[i], c[i+off]);
    }
    double m = c[0];
    #pragma unroll
    for (int off=1; off<64; off<<=1)
      m = fmin(m, __shfl_xor(m, off));
    if (lane == 0){
      unsigned long long kk = (unsigned long long)m;
      idxT[(size_t)pid*KNNq + s] = (int)(kk & 2047ull);
    }
    last = m;
  }
}

// ---------------------------------------------------------------------------
// Kernel 3: fused attn, P=2 points per block; A-weights frag-swizzled.
// LDS repacked with lifetime-based aliasing:
//   unionA: sT (stage3->4) then ctS (stage4->softmax)  [barrier between]
//   unionB: hB (stage1->2) then aggB (softmax->stage5) [barriers between]
// 71 KB -> ~49 KB => 3 blocks/CU instead of 2.
// ---------------------------------------------------------------------------
__global__ __launch_bounds__(256) void k_attn(
  const float* __restrict__ pos,
  const float* __restrict__ valueT, const short* __restrict__ kfT,
  const short* __restrict__ qfT,    const short* __restrict__ vfT,
  const int* __restrict__ idxT,
  const float* __restrict__ pw1, const float* __restrict__ pb1,
  const float* __restrict__ pg,  const float* __restrict__ pbt,
  const float* __restrict__ prm, const float* __restrict__ prv,
  const short* __restrict__ pw2b, const float* __restrict__ pb2,
  const short* __restrict__ aw1b, const float* __restrict__ ab1,
  const float* __restrict__ ag,  const float* __restrict__ abt,
  const float* __restrict__ arm, const float* __restrict__ arv,
  const short* __restrict__ ctwT,
  const short* __restrict__ web,  const float* __restrict__ be,
  float* __restrict__ out)
{
  __shared__ __align__(16) char  unionA[26624];   // sT[48*264]s -> ctS[256*52]s
  __shared__ __align__(16) char  unionB[6912];    // hB[48*72]s  -> aggB[16*72]s
  __shared__ __align__(16) short uT[48*72];       // 6912 B
  __shared__ __align__(16) short vgB[64*56];      // 7168 B
  __shared__ float scS[DMq], sh2S[DMq];           // 2048 B
  __shared__ float prl[3*48];
  __shared__ int   nb[48];

  short* sT   = (short*)unionA;
  short* ctS  = (short*)unionA;
  short* hB   = (short*)unionB;
  short* aggB = (short*)unionB;

  const int t = threadIdx.x;
  const int b  = blockIdx.x >> 10;
  const int n0 = (blockIdx.x & 1023) * 2;
  const int lane = t & 63, quad = lane >> 4, l15 = lane & 15, w = t >> 6;
  const size_t bN = (size_t)b * Nq;

  if (t < 48){
    int p = (t >= 24);
    int k = t - p*24;
    int nn = n0 + p;
    int j = (k < KNNq) ? idxT[(bN + nn)*KNNq + k] : nn;
    nb[t] = j;
    #pragma unroll
    for (int d=0; d<3; d++){
      prl[d*48+t] = pos[((size_t)(b*3+d))*Nq + nn] - pos[((size_t)(b*3+d))*Nq + j];
    }
  }
  {
    float sc = ag[t] * rsqrtf(arv[t] + 1e-5f);
    scS[t]  = sc;
    sh2S[t] = ab1[t]*sc + (abt[t] - arm[t]*sc);
  }
  __syncthreads();

  // ---- stage 1: pos_mlp hidden -> hB ----
  {
    const int ph = t & 63, pkq = t >> 6;
    float sc = pg[ph] * rsqrtf(prv[ph] + 1e-5f);
    float sh = pbt[ph] - prm[ph] * sc;
    float w0 = pw1[ph*3+0], w1 = pw1[ph*3+1], w2 = pw1[ph*3+2];
    float bb = pb1[ph];
    #pragma unroll
    for (int m=0;m<12;m++){
      int pk = pkq + m*4;
      float h = w0*prl[pk] + w1*prl[48+pk] + w2*prl[96+pk] + bb;
      hB[pk*72 + ph] = (short)f2b(fmaxf(h*sc + sh, 0.f));
    }
  }
  __syncthreads();

  // ---- stage 2: pos_emb via MFMA (KS=2); epilogue builds uT, vgB ----
  {
    f32x4 accP[3];
    #pragma unroll
    for (int nt=0;nt<3;nt++) accP[nt]=(f32x4)0.f;
    #pragma unroll
    for (int ks=0;ks<2;ks++){
      const int kcol = ks*32 + quad*8;
      short8 a = *reinterpret_cast<const short8*>(pw2b + ((w*2+ks)*64 + lane)*8);
      #pragma unroll
      for (int nt=0;nt<3;nt++){
        short8 bb = *reinterpret_cast<const short8*>(&hB[(nt*16+l15)*72 + kcol]);
        accP[nt] = __builtin_amdgcn_mfma_f32_16x16x32_bf16(a, bb, accP[nt], 0,0,0);
      }
    }
    const int obase = w*16 + quad*4;
    #pragma unroll
    for (int nt=0;nt<3;nt++){
      int pk = nt*16 + l15;
      int p = (pk >= 24);
      int j = nb[pk];
      int nn = n0 + p;
      short4v q4 = *reinterpret_cast<const short4v*>(qfT + (bN+nn)*Dq + obase);
      short4v k4 = *reinterpret_cast<const short4v*>(kfT + (bN+j)*Dq + obase);
      short4v v4 = *reinterpret_cast<const short4v*>(vfT + (bN+j)*Dq + obase);
      #pragma unroll
      for (int r=0;r<4;r++){
        int o = obase + r;
        float pe = accP[nt][r] + pb2[o];
        uT[pk*72 + o]  = (short)f2b((b2f(q4[r]) - b2f(k4[r])) + pe);
        vgB[o*56 + pk] = (short)f2b(b2f(v4[r]) + pe);
      }
    }
  }
  __syncthreads();   // hB dead from here; unionB free for aggB

  // ---- stage 3: attn conv1 (64->256) MFMA (KS=2); bn+relu -> sT ----
  {
    // zero aggB pad rows 8..15 (hB last read was stage 2; barrier passed)
    for (int i = t; i < 576; i += 256) aggB[576 + i] = 0;

    f32x4 accC[4][3];
    #pragma unroll
    for (int jm=0;jm<4;jm++)
      #pragma unroll
      for (int nt=0;nt<3;nt++) accC[jm][nt]=(f32x4)0.f;
    #pragma unroll
    for (int ks=0;ks<2;ks++){
      const int kcol = ks*32 + quad*8;
      short8 bb[3];
      #pragma unroll
      for (int nt=0;nt<3;nt++)
        bb[nt] = *reinterpret_cast<const short8*>(&uT[(nt*16+l15)*72 + kcol]);
      #pragma unroll
      for (int jm=0;jm<4;jm++){
        int mt = w*4 + jm;
        short8 a = *reinterpret_cast<const short8*>(aw1b + ((mt*2+ks)*64 + lane)*8);
        #pragma unroll
        for (int nt=0;nt<3;nt++)
          accC[jm][nt] = __builtin_amdgcn_mfma_f32_16x16x32_bf16(a, bb[nt], accC[jm][nt], 0,0,0);
      }
    }
    #pragma unroll
    for (int jm=0;jm<4;jm++){
      int cb = (w*4+jm)*16 + quad*4;
      #pragma unroll
      for (int nt=0;nt<3;nt++){
        int pk = nt*16 + l15;
        short4v pkv;
        #pragma unroll
        for (int r=0;r<4;r++){
          int c = cb + r;
          pkv[r] = (short)f2b(fmaxf(accC[jm][nt][r]*scS[c] + sh2S[c], 0.f));
        }
        *reinterpret_cast<short4v*>(&sT[pk*264 + cb]) = pkv;
      }
    }
  }
  __syncthreads();

  // ---- stage 4: convT (256->256) MFMA (KS=8); ct -> ctS (aliases sT) ----
  {
    f32x4 accT[4][3];
    #pragma unroll
    for (int jm=0;jm<4;jm++)
      #pragma unroll
      for (int nt=0;nt<3;nt++) accT[jm][nt]=(f32x4)0.f;
    #pragma unroll
    for (int ks=0;ks<8;ks++){
      const int kcol = ks*32 + quad*8;
      short8 bb[3];
      #pragma unroll
      for (int nt=0;nt<3;nt++)
        bb[nt] = *reinterpret_cast<const short8*>(&sT[(nt*16+l15)*264 + kcol]);
      #pragma unroll
      for (int jm=0;jm<4;jm++){
        int mt = w*4 + jm;
        short8 a = *reinterpret_cast<const short8*>(ctwT + ((mt*8+ks)*64 + lane)*8);
        #pragma unroll
        for (int nt=0;nt<3;nt++)
          accT[jm][nt] = __builtin_amdgcn_mfma_f32_16x16x32_bf16(a, bb[nt], accT[jm][nt], 0,0,0);
      }
    }
    __syncthreads();   // sT fully read; safe to overwrite as ctS
    #pragma unroll
    for (int jm=0;jm<4;jm++){
      #pragma unroll
      for (int nt=0;nt<3;nt++){
        int pk = nt*16 + l15;
        #pragma unroll
        for (int r=0;r<4;r++){
          int row = (w*4+jm)*16 + quad*4 + r;
          ctS[row*52 + pk] = (short)f2b(accT[jm][nt][r]);
        }
      }
    }
  }
  __syncthreads();

  // ---- softmax + aggregate: thread t = row (o,r^), loop p ----
  {
    int o = t >> 2, rr = t & 3;
    #pragma unroll
    for (int p=0;p<2;p++){
      float ct[20], vgv[20];
      #pragma unroll
      for (int q=0;q<5;q++){
        short4v cv  = *reinterpret_cast<const short4v*>(&ctS[t*52 + p*24 + q*4]);
        short4v vv4 = *reinterpret_cast<const short4v*>(&vgB[o*56 + p*24 + q*4]);
        #pragma unroll
        for (int i=0;i<4;i++){ ct[q*4+i]=b2f(cv[i]); vgv[q*4+i]=b2f(vv4[i]); }
      }
      float m = ct[0];
      #pragma unroll
      for (int k=1;k<20;k++) m = fmaxf(m, ct[k]);
      float s = 0.f, a = 0.f;
      #pragma unroll
      for (int k=0;k<20;k++){
        float e = __expf(ct[k]-m);
        s += e;
        a = fmaf(e, vgv[k], a);
      }
      aggB[(p*4+rr)*72 + o] = (short)f2b(a/s);
    }
  }
  __syncthreads();

  // ---- stage 5: conv_end (64->256) MFMA (KS=2) + bias + identity ----
  {
    f32x4 accE[4];
    #pragma unroll
    for (int jm=0;jm<4;jm++) accE[jm]=(f32x4)0.f;
    #pragma unroll
    for (int ks=0;ks<2;ks++){
      const int kcol = ks*32 + quad*8;
      short8 bb = *reinterpret_cast<const short8*>(&aggB[l15*72 + kcol]);
      #pragma unroll
      for (int jm=0;jm<4;jm++){
        int mt = w*4 + jm;
        short8 a = *reinterpret_cast<const short8*>(web + ((mt*2+ks)*64 + lane)*8);
        accE[jm] = __builtin_amdgcn_mfma_f32_16x16x32_bf16(a, bb, accE[jm], 0,0,0);
      }
    }
    if (l15 < 8){
      int p = l15 >> 2, rr = l15 & 3;
      #pragma unroll
      for (int jm=0;jm<4;jm++){
        #pragma unroll
        for (int r=0;r<4;r++){
          int c = (w*4+jm)*16 + quad*4 + r;
          float y = accE[jm][r] + be[c] + valueT[(bN + n0 + p)*Cq + c];
          out[((size_t)(b*Cq+c))*((size_t)Nq*UPq) + (size_t)(n0+p)*UPq + rr] = y;
        }
      }
    }
  }
}

// ---------------------------------------------------------------------------
extern "C" void kernel_launch(void* const* d_in, const int* in_sizes, int n_in,
                              void* d_out, int out_size, void* d_ws, size_t ws_size,
                              hipStream_t stream)
{
  const float* pos  = (const float*)d_in[0];
  const float* key  = (const float*)d_in[1];
  const float* qry  = (const float*)d_in[2];
  const float* wv1  = (const float*)d_in[3];
  const float* bv1  = (const float*)d_in[4];
  const float* wv2  = (const float*)d_in[5];
  const float* bv2  = (const float*)d_in[6];
  const float* wvs  = (const float*)d_in[7];
  const float* bvs  = (const float*)d_in[8];
  const float* wk   = (const float*)d_in[9];
  const float* bk   = (const float*)d_in[10];
  const float* wq   = (const float*)d_in[11];
  const float* bq   = (const float*)d_in[12];
  const float* wval = (const float*)d_in[13];
  const float* bval = (const float*)d_in[14];
  const float* pw1  = (const float*)d_in[15];
  const float* pb1  = (const float*)d_in[16];
  const float* pg   = (const float*)d_in[17];
  const float* pbt  = (const float*)d_in[18];
  const float* prm  = (const float*)d_in[19];
  const float* prv  = (const float*)d_in[20];
  const float* pw2  = (const float*)d_in[21];
  const float* pb2  = (const float*)d_in[22];
  const float* aw1  = (const float*)d_in[23];
  const float* ab1  = (const float*)d_in[24];
  const float* ag   = (const float*)d_in[25];
  const float* abt  = (const float*)d_in[26];
  const float* arm  = (const float*)d_in[27];
  const float* arv  = (const float*)d_in[28];
  const float* ctw  = (const float*)d_in[29];
  const float* we   = (const float*)d_in[31];
  const float* be   = (const float*)d_in[32];

  char* ws = (char*)d_ws;
  float* valueT = (float*)(ws);                    // 8 MB fp32
  short* kfT    = (short*)(ws + 8388608);          // 1 MB bf16
  short* qfT    = (short*)(ws + 9437184);
  short* vfT    = (short*)(ws + 10485760);
  int*   idxT   = (int*)  (ws + 11534336);         // 640 KB
  short* aw1b   = (short*)(ws + 12189696);         // 32 KB
  short* ctwT   = (short*)(ws + 12222464);         // 128 KB
  short* wv1b   = (short*)(ws + 12353536);         // 256 KB
  short* wvsb   = (short*)(ws + 12615680);         // 256 KB
  short* wv2b   = (short*)(ws + 12877824);         // 128 KB
  short* wkb    = (short*)(ws + 13008896);         // 32 KB
  short* wqb    = (short*)(ws + 13041664);         // 32 KB
  short* wvalb  = (short*)(ws + 13074432);         // 32 KB
  short* pw2b   = (short*)(ws + 13107200);         // 8 KB
  short* web    = (short*)(ws + 13115392);         // 32 KB
  float* out    = (float*)d_out;

  k_prep<<<dim3(1872), dim3(256), 0, stream>>>(
      aw1, ctw, wv1, wvs, wv2, wk, wq, wval, pw2, we,
      aw1b, ctwT, wv1b, wvsb, wv2b, wkb, wqb, wvalb, pw2b, web);
  k_value<<<dim3(Bq*Nq/PTS), dim3(256), 0, stream>>>(
      key, qry, wv1b, wvsb, wv2b, wkb, wqb, wvalb,
      bv1, bv2, bvs, bk, bq, bval,
      valueT, kfT, qfT, vfT);
  k_knn<<<dim3(Bq*Nq/4), dim3(256), 0, stream>>>(pos, idxT);
  k_attn<<<dim3(Bq*Nq/2), dim3(256), 0, stream>>>(
      pos, valueT, kfT, qfT, vfT, idxT,
      pw1, pb1, pg, pbt, prm, prv, pw2b, pb2,
      aw1b, ab1, ag, abt, arm, arv, ctwT, web, be, out);
}